// Round 6
// baseline (345.562 us; speedup 1.0000x reference)
//
#include <hip/hip_runtime.h>

// TranslationIPA: B=1, N=512, CS=384, CZ=128, H=8, C=256, PQ=8, PV=12
// feats layout: [o 2048 | x 96 | y 96 | z 96 | norm 96 | o_pair 256] = 2688

// workspace float offsets
#define OFF_QBH    0          // qbh  us[512*2048]
#define OFF_KBH    524288     // kbh  us[512*2048]
#define OFF_VB     1048576    // vb   f32[512*2048]
#define OFF_QPRAW  2097152    // f32[512*192]
#define OFF_KVPRAW 2195456    // f32[512*480]
#define OFF_BBIAS  2785280    // us[8*262144]  ([h][i*512+j] bf16)
#define OFF_PAIRZT 3833856    // us[512*32*512] ([i][d][j] bf16)
#define OFF_ATTNH  8028160    // us[8*512*512] ([h][i][j] bf16)
#define OFF_FEATSB 9076736    // us[512*2688] bf16
#define OFF_WCAT   9764864    // us[48*128]
#define OFF_WTALL  9767936    // us[6848*384]
#define OFF_VPT    11082752   // us[8*352*512]
#define OFF_WOT    11803648   // us[384*2688]
#define OFF_QPTH   12319744   // us[8*512*32]
#define OFF_QPTL   12385280   // us[8*512*32]
#define OFF_KPTH   12450816   // us[8*512*32]
#define OFF_KPTL   12516352   // us[8*512*32]
#define OFF_QP2    12581888   // f32[8*512]
#define OFF_KP2    12585984   // f32[8*512]
#define OFF_SBF    12590080   // us[512*384] bf16 copy of s

typedef __attribute__((ext_vector_type(8))) short short8;   // 8 bf16
typedef __attribute__((ext_vector_type(4))) float f32x4;

__device__ __forceinline__ unsigned short f2bf(float f) {   // RNE f32 -> bf16
  union { float f; unsigned u; } v; v.f = f;
  unsigned u = v.u;
  unsigned r = (u + 0x7fffu + ((u >> 16) & 1u)) >> 16;
  return (unsigned short)r;
}
__device__ __forceinline__ float bf2f(unsigned short h) {
  union { unsigned u; float f; } v; v.u = ((unsigned)h) << 16; return v.f;
}
__device__ __forceinline__ short8 pack8(float4 a, float4 b) {
  short8 r;
  r[0] = (short)f2bf(a.x); r[1] = (short)f2bf(a.y);
  r[2] = (short)f2bf(a.z); r[3] = (short)f2bf(a.w);
  r[4] = (short)f2bf(b.x); r[5] = (short)f2bf(b.y);
  r[6] = (short)f2bf(b.z); r[7] = (short)f2bf(b.w);
  return r;
}

// ---------------- prep_all: all weight transposes + s->bf16, one launch -------------
__global__ __launch_bounds__(256) void prep_all(
    const float* __restrict__ wq, const float* __restrict__ wkv,
    const float* __restrict__ wqp, const float* __restrict__ wkvp,
    const float* __restrict__ wo, const float* __restrict__ wb,
    const float* __restrict__ wz, const float* __restrict__ s,
    unsigned short* __restrict__ wTall, unsigned short* __restrict__ woT,
    unsigned short* __restrict__ wT, unsigned short* __restrict__ sbf) {
  __shared__ float tile[64][65];
  const int b = blockIdx.x, t = threadIdx.x;
  if (b < 642) {
    const int ntile = b % 107, kt = b / 107;
    const float* src; int Nsrc, nloc0;
    const int ng0 = ntile * 64;
    if (ntile < 32)      { src = wq;   Nsrc = 2048; nloc0 = ng0; }
    else if (ntile < 96) { src = wkv;  Nsrc = 4096; nloc0 = ng0 - 2048; }
    else if (ntile < 99) { src = wqp;  Nsrc = 192;  nloc0 = ng0 - 6144; }
    else                 { src = wkvp; Nsrc = 480;  nloc0 = ng0 - 6336; }
    const int r = t >> 2, cs = (t & 3) * 16;
#pragma unroll
    for (int i = 0; i < 16; i += 4) {
      int n = nloc0 + cs + i;
      float4 v;
      if (n + 3 < Nsrc) v = *(const float4*)(src + (size_t)(kt * 64 + r) * Nsrc + n);
      else {
        v.x = (n + 0 < Nsrc) ? src[(size_t)(kt * 64 + r) * Nsrc + n + 0] : 0.f;
        v.y = (n + 1 < Nsrc) ? src[(size_t)(kt * 64 + r) * Nsrc + n + 1] : 0.f;
        v.z = (n + 2 < Nsrc) ? src[(size_t)(kt * 64 + r) * Nsrc + n + 2] : 0.f;
        v.w = (n + 3 < Nsrc) ? src[(size_t)(kt * 64 + r) * Nsrc + n + 3] : 0.f;
      }
      tile[r][cs + i + 0] = v.x; tile[r][cs + i + 1] = v.y;
      tile[r][cs + i + 2] = v.z; tile[r][cs + i + 3] = v.w;
    }
    __syncthreads();
    const int nr = t >> 2, ks = (t & 3) * 16;
    unsigned short ov[16];
#pragma unroll
    for (int i = 0; i < 16; i++) ov[i] = f2bf(tile[ks + i][nr]);
    unsigned short* dst = wTall + (size_t)(ng0 + nr) * 384 + kt * 64 + ks;
    *(uint4*)(dst) = *(const uint4*)&ov[0];
    *(uint4*)(dst + 8) = *(const uint4*)&ov[8];
  } else if (b < 894) {
    const int idx = b - 642;
    const int kt = idx % 42, ntile = idx / 42;
    const int r = t >> 2, cs = (t & 3) * 16;
#pragma unroll
    for (int i = 0; i < 16; i += 4) {
      float4 v = *(const float4*)(wo + (size_t)(kt * 64 + r) * 384 + ntile * 64 + cs + i);
      tile[r][cs + i + 0] = v.x; tile[r][cs + i + 1] = v.y;
      tile[r][cs + i + 2] = v.z; tile[r][cs + i + 3] = v.w;
    }
    __syncthreads();
    const int nr = t >> 2, ks = (t & 3) * 16;
    unsigned short ov[16];
#pragma unroll
    for (int i = 0; i < 16; i++) ov[i] = f2bf(tile[ks + i][nr]);
    unsigned short* dst = woT + (size_t)(ntile * 64 + nr) * 2688 + kt * 64 + ks;
    *(uint4*)(dst) = *(const uint4*)&ov[0];
    *(uint4*)(dst + 8) = *(const uint4*)&ov[8];
  } else if (b < 918) {
    const int l = (b - 894) * 256 + t;  // 48*128 = 6144
    if (l < 6144) {
      int n = l >> 7, k = l & 127;
      float v = (n < 8) ? wb[k * 8 + n] * 0.5773502691896258f
                        : (n < 40 ? wz[k * 32 + (n - 8)] : 0.f);
      wT[l] = f2bf(v);
    }
  } else {
    const int gid = (b - 918) * 256 + t;       // 24576 threads x 8 elems
    const int off = gid * 8;                   // covers 512*384 = 196608
    float4 a0 = *(const float4*)(s + off);
    float4 a1 = *(const float4*)(s + off + 4);
    *(short8*)(sbf + off) = pack8(a0, a1);
  }
}

// ---------------- mega1: VALU-zpass (blocks [0,1024)) U proj ([1024,1880)) ----------
// zpass: thread = one z-row (skinny GEMM M=262k,K=128,N=40 -> VALU roofline ~17us).
// Streaming float4 loads (32 indep per thread, no per-tile vmcnt(0) barrier),
// wT broadcast from LDS, all 40 stores coalesced (lane=j contiguous).
__global__ __launch_bounds__(256) void mega1(
    const float* __restrict__ z, const unsigned short* __restrict__ wT,
    const float* __restrict__ bb, const float* __restrict__ bz,
    unsigned short* __restrict__ bbias_tb, unsigned short* __restrict__ pairzT,
    const unsigned short* __restrict__ sbf, const unsigned short* __restrict__ wTall,
    const float* __restrict__ bq, const float* __restrict__ bkv,
    const float* __restrict__ bqp, const float* __restrict__ bkvp,
    unsigned short* __restrict__ qbh, unsigned short* __restrict__ kbh,
    float* __restrict__ vb, float* __restrict__ qpraw, float* __restrict__ kvpraw) {
  const int lane = threadIdx.x & 63, wv = threadIdx.x >> 6;
  const int quad = lane >> 4, m = lane & 15;
  if (blockIdx.x < 1024) {
    // ------- VALU zpass: block b covers rows [b*256, +256) = i = b>>1, j-half b&1 ---
    __shared__ float wTl[40][128];
    const int t = threadIdx.x;
    for (int l = t; l < 5120; l += 256)
      wTl[l >> 7][l & 127] = bf2f(wT[l]);
    __syncthreads();
    const int i = blockIdx.x >> 1;
    const int j = (blockIdx.x & 1) * 256 + t;
    const int row = i * 512 + j;
    float acc[40];
#pragma unroll
    for (int n = 0; n < 40; n++) acc[n] = 0.f;
    const float* zr = z + (size_t)row * 128;
#pragma unroll 4
    for (int kq = 0; kq < 32; kq++) {
      float4 zv = *(const float4*)(zr + kq * 4);
#pragma unroll
      for (int n = 0; n < 40; n++) {
        float4 wv4 = *(const float4*)&wTl[n][kq * 4];
        acc[n] = fmaf(zv.x, wv4.x, acc[n]);
        acc[n] = fmaf(zv.y, wv4.y, acc[n]);
        acc[n] = fmaf(zv.z, wv4.z, acc[n]);
        acc[n] = fmaf(zv.w, wv4.w, acc[n]);
      }
    }
#pragma unroll
    for (int c = 0; c < 8; c++)
      bbias_tb[(size_t)c * 262144 + row] = f2bf(acc[c] + 0.5773502691896258f * bb[c]);
#pragma unroll
    for (int d = 0; d < 32; d++)
      pairzT[((size_t)i * 32 + d) * 512 + j] = f2bf(acc[8 + d] + bz[d]);
  } else {
    // ------- proj -------
    const int b2 = blockIdx.x - 1024;
    const int bx = b2 % 107, row0 = (b2 / 107) * 64;
    const int n0 = bx * 64;
    const unsigned short* srow = sbf + (size_t)(row0 + wv * 16 + m) * 384;
    f32x4 acc[4];
#pragma unroll
    for (int nt = 0; nt < 4; nt++) acc[nt] = (f32x4){0.f, 0.f, 0.f, 0.f};
#pragma unroll
    for (int ksx = 0; ksx < 12; ksx++) {
      const int c0 = ksx * 32 + quad * 8;
      short8 af = *(const short8*)(srow + c0);
#pragma unroll
      for (int nt = 0; nt < 4; nt++) {
        short8 bfw = *(const short8*)(wTall + (size_t)(n0 + nt * 16 + m) * 384 + c0);
        acc[nt] = __builtin_amdgcn_mfma_f32_16x16x32_bf16(af, bfw, acc[nt], 0, 0, 0);
      }
    }
    const int rbase = row0 + wv * 16 + quad * 4;
#pragma unroll
    for (int nt = 0; nt < 4; nt++) {
      const int col = n0 + nt * 16 + m;
      if (n0 < 2048) {
        const float bias = bq[col];
#pragma unroll
        for (int r = 0; r < 4; r++)
          qbh[(size_t)(rbase + r) * 2048 + col] = f2bf(acc[nt][r] + bias);
      } else if (n0 < 6144) {
        const int ckv = col - 2048;
        const float bias = bkv[ckv];
        const int hh = ckv >> 9, c = ckv & 511;
        if (c < 256) {
#pragma unroll
          for (int r = 0; r < 4; r++)
            kbh[(size_t)(rbase + r) * 2048 + hh * 256 + c] = f2bf(acc[nt][r] + bias);
        } else {
#pragma unroll
          for (int r = 0; r < 4; r++)
            vb[(size_t)(rbase + r) * 2048 + hh * 256 + (c - 256)] = acc[nt][r] + bias;
        }
      } else if (n0 < 6336) {
        const int cq = col - 6144;
        const float bias = bqp[cq];
#pragma unroll
        for (int r = 0; r < 4; r++)
          qpraw[(size_t)(rbase + r) * 192 + cq] = acc[nt][r] + bias;
      } else {
        const int ck = col - 6336;
        if (ck < 480) {
          const float bias = bkvp[ck];
#pragma unroll
          for (int r = 0; r < 4; r++)
            kvpraw[(size_t)(rbase + r) * 480 + ck] = acc[nt][r] + bias;
        }
      }
    }
  }
}

// ---------------- mega2: vpt_prep (blocks [0,320)) U pts_planes ([320,336)) ---------
__global__ __launch_bounds__(256) void mega2(
    const float* __restrict__ vb, const float* __restrict__ qpraw,
    const float* __restrict__ kvpraw, const float* __restrict__ rot,
    const float* __restrict__ trans, unsigned short* __restrict__ vptT,
    unsigned short* __restrict__ qptH, unsigned short* __restrict__ qptL,
    unsigned short* __restrict__ kptH, unsigned short* __restrict__ kptL,
    float* __restrict__ qp2g, float* __restrict__ kp2g) {
  __shared__ float tile[64][65];
  const int b = blockIdx.x, t = threadIdx.x;
  if (b < 320) {
    const int jt = b & 7, h = (b >> 3) & 7, part = b >> 6;
    const int j0 = jt * 64;
    if (part < 4) {
      const int c0 = part * 64;
      const int r = t >> 2, cs = (t & 3) * 16;
#pragma unroll
      for (int ii = 0; ii < 16; ii += 4) {
        float4 v = *(const float4*)(vb + (size_t)(j0 + r) * 2048 + h * 256 + c0 + cs + ii);
        tile[r][cs + ii + 0] = v.x; tile[r][cs + ii + 1] = v.y;
        tile[r][cs + ii + 2] = v.z; tile[r][cs + ii + 3] = v.w;
      }
      __syncthreads();
      const int cl = t >> 2, js = (t & 3) * 16;
      unsigned short ov[16];
#pragma unroll
      for (int x = 0; x < 16; x++) ov[x] = f2bf(tile[js + x][cl]);
      unsigned short* dst = vptT + ((size_t)h * 352 + c0 + cl) * 512 + j0 + js;
      *(uint4*)dst = *(const uint4*)&ov[0];
      *(uint4*)(dst + 8) = *(const uint4*)&ov[8];
    } else {
      float (*lds)[37] = (float(*)[37])&tile[0][0];   // 64 x 37 view
      for (int l = t; l < 64 * 36; l += 256) {
        int jl = l / 36, w = l % 36;
        int p = w / 3, d = w % 3;
        const int n = j0 + jl;
        const int pidx = h * 20 + 8 + p;
        const float* kr = kvpraw + (size_t)n * 480;
        float px = kr[pidx], py = kr[160 + pidx], pz = kr[320 + pidx];
        const float* R = rot + n * 9;
        lds[jl][w] = R[d * 3 + 0] * px + R[d * 3 + 1] * py + R[d * 3 + 2] * pz + trans[n * 3 + d];
      }
      __syncthreads();
#pragma unroll
      for (int step = 0; step < 3; step++) {
        int chunk = t + 256 * step;          // < 768 = 96 rows x 8 chunks
        int row = chunk >> 3, js = (chunk & 7) * 8;
        unsigned short ov[8];
#pragma unroll
        for (int x = 0; x < 8; x++) {
          int w = (row < 48) ? row : row - 48;
          float f = (w < 36) ? lds[js + x][w] : 0.f;
          unsigned short hi = f2bf(f);
          ov[x] = (row < 48) ? hi : f2bf(f - bf2f(hi));
        }
        *(uint4*)(vptT + ((size_t)h * 352 + 256 + row) * 512 + j0 + js) = *(const uint4*)&ov[0];
      }
    }
  } else {
    // ------- pts_planes with inline rigid -------
    const int idx = b - 320;
    const int row = (idx & 1) * 256 + t;
    const int h = idx >> 1;
    const float* R  = rot + row * 9;
    const float* tr = trans + row * 3;
    {
      const float* qr = qpraw + (size_t)row * 192;
      unsigned short hi[32], lo[32]; float s2 = 0.f;
#pragma unroll
      for (int p = 0; p < 8; p++) {
        const int pidx = h * 8 + p;
        float px = qr[pidx], py = qr[64 + pidx], pz = qr[128 + pidx];
        float X = R[0] * px + R[1] * py + R[2] * pz + tr[0];
        float Y = R[3] * px + R[4] * py + R[5] * pz + tr[1];
        float Z = R[6] * px + R[7] * py + R[8] * pz + tr[2];
        hi[p * 3 + 0] = f2bf(X); lo[p * 3 + 0] = f2bf(X - bf2f(hi[p * 3 + 0]));
        hi[p * 3 + 1] = f2bf(Y); lo[p * 3 + 1] = f2bf(Y - bf2f(hi[p * 3 + 1]));
        hi[p * 3 + 2] = f2bf(Z); lo[p * 3 + 2] = f2bf(Z - bf2f(hi[p * 3 + 2]));
        s2 += X * X + Y * Y + Z * Z;
      }
#pragma unroll
      for (int w = 24; w < 32; w++) { hi[w] = 0; lo[w] = 0; }
      unsigned short* dh = qptH + ((size_t)h * 512 + row) * 32;
      unsigned short* dl = qptL + ((size_t)h * 512 + row) * 32;
#pragma unroll
      for (int g = 0; g < 4; g++) {
        *(uint4*)(dh + g * 8) = *(const uint4*)&hi[g * 8];
        *(uint4*)(dl + g * 8) = *(const uint4*)&lo[g * 8];
      }
      qp2g[h * 512 + row] = s2;
    }
    {
      const float* kr = kvpraw + (size_t)row * 480;
      unsigned short hi[32], lo[32]; float s2 = 0.f;
#pragma unroll
      for (int p = 0; p < 8; p++) {
        const int pidx = h * 20 + p;
        float px = kr[pidx], py = kr[160 + pidx], pz = kr[320 + pidx];
        float X = R[0] * px + R[1] * py + R[2] * pz + tr[0];
        float Y = R[3] * px + R[4] * py + R[5] * pz + tr[1];
        float Z = R[6] * px + R[7] * py + R[8] * pz + tr[2];
        hi[p * 3 + 0] = f2bf(X); lo[p * 3 + 0] = f2bf(X - bf2f(hi[p * 3 + 0]));
        hi[p * 3 + 1] = f2bf(Y); lo[p * 3 + 1] = f2bf(Y - bf2f(hi[p * 3 + 1]));
        hi[p * 3 + 2] = f2bf(Z); lo[p * 3 + 2] = f2bf(Z - bf2f(hi[p * 3 + 2]));
        s2 += X * X + Y * Y + Z * Z;
      }
#pragma unroll
      for (int w = 24; w < 32; w++) { hi[w] = 0; lo[w] = 0; }
      unsigned short* dh = kptH + ((size_t)h * 512 + row) * 32;
      unsigned short* dl = kptL + ((size_t)h * 512 + row) * 32;
#pragma unroll
      for (int g = 0; g < 4; g++) {
        *(uint4*)(dh + g * 8) = *(const uint4*)&hi[g * 8];
        *(uint4*)(dl + g * 8) = *(const uint4*)&lo[g * 8];
      }
      kp2g[h * 512 + row] = s2;
    }
  }
}

// ---------------- fused logits + softmax + a@[v,pts], 8 waves ------------------------
__global__ __launch_bounds__(512) void logits_fused(
    const unsigned short* __restrict__ qbh, const unsigned short* __restrict__ kbh,
    const unsigned short* __restrict__ qptH, const unsigned short* __restrict__ qptL,
    const unsigned short* __restrict__ kptH, const unsigned short* __restrict__ kptL,
    const float* __restrict__ qp2g, const float* __restrict__ kp2g,
    const unsigned short* __restrict__ bbias_tb, const float* __restrict__ mask,
    const float* __restrict__ hwp, const unsigned short* __restrict__ vptT,
    const float* __restrict__ rot, const float* __restrict__ trans,
    unsigned short* __restrict__ attnh, unsigned short* __restrict__ featsb) {
  const int it = blockIdx.x, h = blockIdx.y;
  const int i0 = it * 16;
  __shared__ __align__(16) unsigned short sth[8][16][72], stl[8][16][72];
  __shared__ float redm[16][8], reds[16][8];
  __shared__ float lds_h[16][48], lds_l[16][48];
  const int t = threadIdx.x;
  const int lane = t & 63, wv = t >> 6;
  const int quad = lane >> 4, m = lane & 15;
  const int jw0 = wv * 64;

  // ---- QK^T (4 n-tiles of 16 j each) ----
  f32x4 acc[4];
#pragma unroll
  for (int nt = 0; nt < 4; nt++) acc[nt] = (f32x4){0.f, 0.f, 0.f, 0.f};
  const unsigned short* qrow = qbh + (size_t)(i0 + m) * 2048 + h * 256;
#pragma unroll
  for (int s = 0; s < 8; s++) {
    short8 af = *(const short8*)(qrow + s * 32 + quad * 8);
#pragma unroll
    for (int nt = 0; nt < 4; nt++) {
      short8 bfr = *(const short8*)(kbh + (size_t)(jw0 + nt * 16 + m) * 2048 + h * 256 + s * 32 + quad * 8);
      acc[nt] = __builtin_amdgcn_mfma_f32_16x16x32_bf16(af, bfr, acc[nt], 0, 0, 0);
    }
  }

  // ---- point cross-term (hi/lo split) from global planes ----
  short8 aqh = *(const short8*)(qptH + ((size_t)h * 512 + i0 + m) * 32 + quad * 8);
  short8 aql = *(const short8*)(qptL + ((size_t)h * 512 + i0 + m) * 32 + quad * 8);
  f32x4 accp[4];
#pragma unroll
  for (int nt = 0; nt < 4; nt++) {
    const size_t krow = ((size_t)h * 512 + jw0 + nt * 16 + m) * 32 + quad * 8;
    short8 bkh = *(const short8*)(kptH + krow);
    short8 bkl = *(const short8*)(kptL + krow);
    f32x4 p = (f32x4){0.f, 0.f, 0.f, 0.f};
    p = __builtin_amdgcn_mfma_f32_16x16x32_bf16(aqh, bkh, p, 0, 0, 0);
    p = __builtin_amdgcn_mfma_f32_16x16x32_bf16(aqh, bkl, p, 0, 0, 0);
    p = __builtin_amdgcn_mfma_f32_16x16x32_bf16(aql, bkh, p, 0, 0, 0);
    accp[nt] = p;
  }

  // ---- logits ----
  const float c1 = 0.03608439182435161f;                         // 1/sqrt(768)
  const float hw = log1pf(expf(hwp[h])) * 0.09622504486493764f;  // softplus*sqrt(1/108)
  float qp2v[4];
#pragma unroll
  for (int r = 0; r < 4; r++) qp2v[r] = qp2g[h * 512 + i0 + quad * 4 + r];
  float lg[4][4];
  float rmax[4] = {-1e30f, -1e30f, -1e30f, -1e30f};
#pragma unroll
  for (int nt = 0; nt < 4; nt++) {
    const int j = jw0 + nt * 16 + m;
    const float kp2v = kp2g[h * 512 + j];
    const float mj = mask[j];
#pragma unroll
    for (int r = 0; r < 4; r++) {
      const int il = quad * 4 + r;
      const float pt = qp2v[r] + kp2v - 2.f * accp[nt][r];
      float v = c1 * acc[nt][r]
              + bf2f(bbias_tb[(size_t)h * 262144 + (size_t)(i0 + il) * 512 + j])
              - 0.5f * hw * pt
              + 100000.f * (mask[i0 + il] * mj - 1.f);
      lg[nt][r] = v;
      rmax[r] = fmaxf(rmax[r], v);
    }
  }
  // ---- softmax (cross-lane within 16-lane group, then cross-wave via LDS) ----
#pragma unroll
  for (int r = 0; r < 4; r++) {
#pragma unroll
    for (int off = 1; off < 16; off <<= 1) rmax[r] = fmaxf(rmax[r], __shfl_xor(rmax[r], off));
  }
  if (m == 0) {
#pragma unroll
    for (int r = 0; r < 4; r++) redm[quad * 4 + r][wv] = rmax[r];
  }
  __syncthreads();
  float rowm[4], rsum[4];
#pragma unroll
  for (int r = 0; r < 4; r++) {
    const int il = quad * 4 + r;
    float m0 = fmaxf(fmaxf(redm[il][0], redm[il][1]), fmaxf(redm[il][2], redm[il][3]));
    float m1 = fmaxf(fmaxf(redm[il][4], redm[il][5]), fmaxf(redm[il][6], redm[il][7]));
    rowm[r] = fmaxf(m0, m1);
    rsum[r] = 0.f;
  }
#pragma unroll
  for (int nt = 0; nt < 4; nt++)
#pragma unroll
    for (int r = 0; r < 4; r++) {
      float e = __expf(lg[nt][r] - rowm[r]);
      lg[nt][r] = e;
      rsum[r] += e;
    }
#pragma unroll
  for (int r = 0; r < 4; r++) {
#pragma unroll
    for (int off = 1; off < 16; off <<= 1) rsum[r] += __shfl_xor(rsum[r], off);
  }
  if (m == 0) {
#pragma unroll
    for (int r = 0; r < 4; r++) reds[quad * 4 + r][wv] = rsum[r];
  }
  __syncthreads();
  float inv[4];
#pragma unroll
  for (int r = 0; r < 4; r++) {
    const int il = quad * 4 + r;
    float s0 = (reds[il][0] + reds[il][1]) + (reds[il][2] + reds[il][3]);
    float s1 = (reds[il][4] + reds[il][5]) + (reds[il][6] + reds[il][7]);
    inv[r] = 1.f / (s0 + s1);
  }
  // ---- a -> bf16 hi/lo into LDS ----
#pragma unroll
  for (int nt = 0; nt < 4; nt++)
#pragma unroll
    for (int r = 0; r < 4; r++) {
      const int il = quad * 4 + r;
      float a = lg[nt][r] * inv[r];
      unsigned short hi = f2bf(a);
      sth[wv][il][nt * 16 + m] = hi;
      stl[wv][il][nt * 16 + m] = f2bf(a - bf2f(hi));
    }
  __syncthreads();
  // attnh global (hi only, for o_pair), coalesced: 16 rows x 8 segs of 8 per wave
#pragma unroll
  for (int step = 0; step < 2; step++) {
    const int idx = lane + 64 * step;        // 0..127
    const int il = idx >> 3, seg = idx & 7;
    uint4 vh = *(const uint4*)&sth[wv][il][seg * 8];
    *(uint4*)(attnh + ((size_t)h * 512 + i0 + il) * 512 + jw0 + seg * 8) = vh;
  }

  // ---- phase 2: a @ vptT (A-frags from LDS across all 8 j-slices) ----
  const int nt0 = (wv < 6) ? wv * 3 : 18 + (wv - 6) * 2;
  const int ncnt = (wv < 6) ? 3 : 2;
  f32x4 vacc[3];
#pragma unroll
  for (int k = 0; k < 3; k++) vacc[k] = (f32x4){0.f, 0.f, 0.f, 0.f};
  const unsigned short* vbase = vptT + (size_t)h * 352 * 512;
#pragma unroll
  for (int s = 0; s < 16; s++) {
    const int wsrc = s >> 1, col = (s & 1) * 32 + quad * 8;
    short8 ah = *(const short8*)&sth[wsrc][m][col];
    short8 al = *(const short8*)&stl[wsrc][m][col];
    const int ko = s * 32 + quad * 8;
#pragma unroll
    for (int k = 0; k < 3; k++) {
      if (k < ncnt) {
        const int nt = nt0 + k;
        short8 bfr = *(const short8*)(vbase + (size_t)(nt * 16 + m) * 512 + ko);
        vacc[k] = __builtin_amdgcn_mfma_f32_16x16x32_bf16(ah, bfr, vacc[k], 0, 0, 0);
        if (nt >= 16 && nt < 19)
          vacc[k] = __builtin_amdgcn_mfma_f32_16x16x32_bf16(al, bfr, vacc[k], 0, 0, 0);
      }
    }
  }
#pragma unroll
  for (int k = 0; k < 3; k++) {
    if (k < ncnt) {
      const int nt = nt0 + k;
      if (nt < 16) {
#pragma unroll
        for (int r = 0; r < 4; r++)
          featsb[(size_t)(i0 + quad * 4 + r) * 2688 + h * 256 + nt * 16 + m] = f2bf(vacc[k][r]);
      } else if (nt < 19) {
        const int w = (nt - 16) * 16 + m;
#pragma unroll
        for (int r = 0; r < 4; r++) if (w < 36) lds_h[quad * 4 + r][w] = vacc[k][r];
      } else {
        const int w = (nt - 19) * 16 + m;
#pragma unroll
        for (int r = 0; r < 4; r++) if (w < 36) lds_l[quad * 4 + r][w] = vacc[k][r];
      }
    }
  }
  __syncthreads();
  if (t < 192) {
    const int il = t / 12, p = t % 12, irow = i0 + il;
    const float* R = rot + irow * 9;
    const float* tr = trans + irow * 3;
    float x  = lds_h[il][p * 3 + 0] + lds_l[il][p * 3 + 0] - tr[0];
    float y  = lds_h[il][p * 3 + 1] + lds_l[il][p * 3 + 1] - tr[1];
    float zz = lds_h[il][p * 3 + 2] + lds_l[il][p * 3 + 2] - tr[2];
    float o0 = R[0] * x + R[3] * y + R[6] * zz;   // R^T v
    float o1 = R[1] * x + R[4] * y + R[7] * zz;
    float o2 = R[2] * x + R[5] * y + R[8] * zz;
    float nrm = sqrtf(o0 * o0 + o1 * o1 + o2 * o2 + 1e-8f);
    unsigned short* fr = featsb + (size_t)irow * 2688 + 2048;
    fr[h * 12 + p]       = f2bf(o0);
    fr[96 + h * 12 + p]  = f2bf(o1);
    fr[192 + h * 12 + p] = f2bf(o2);
    fr[288 + h * 12 + p] = f2bf(nrm);
  }
}

// ---------------- o_pair via MFMA: per-i [8h x 512j] @ [512j x 32d] ------------------
__global__ __launch_bounds__(256) void o_pair_mfma(
    const unsigned short* __restrict__ attnh, const unsigned short* __restrict__ pairzT,
    unsigned short* __restrict__ featsb) {
  const int lane = threadIdx.x & 63, wv = threadIdx.x >> 6;
  const int quad = lane >> 4, m = lane & 15;
  const int i = blockIdx.x * 4 + wv;          // grid 128
  f32x4 acc[2];
  acc[0] = (f32x4){0.f, 0.f, 0.f, 0.f};
  acc[1] = (f32x4){0.f, 0.f, 0.f, 0.f};
#pragma unroll
  for (int s = 0; s < 16; s++) {
    const int ko = s * 32 + quad * 8;
    short8 af = *(const short8*)(attnh + (size_t)(m & 7) * 262144 + (size_t)i * 512 + ko);
#pragma unroll
    for (int nt = 0; nt < 2; nt++) {
      short8 bfr = *(const short8*)(pairzT + ((size_t)i * 32 + nt * 16 + m) * 512 + ko);
      acc[nt] = __builtin_amdgcn_mfma_f32_16x16x32_bf16(af, bfr, acc[nt], 0, 0, 0);
    }
  }
  if (quad < 2) {
#pragma unroll
    for (int nt = 0; nt < 2; nt++)
#pragma unroll
      for (int r = 0; r < 4; r++) {
        const int hh = quad * 4 + r, d = nt * 16 + m;
        featsb[(size_t)i * 2688 + 2432 + hh * 32 + d] = f2bf(acc[nt][r]);
      }
  }
}

// ---------------- out = featsb @ woT^T + bo via MFMA (no atomics) -------------------
__global__ __launch_bounds__(256) void out_mfma(
    const unsigned short* __restrict__ featsb, const unsigned short* __restrict__ woT,
    const float* __restrict__ bo, float* __restrict__ out) {
  const int it = blockIdx.x, ng = blockIdx.y;   // grid (32, 6)
  const int lane = threadIdx.x & 63, wv = threadIdx.x >> 6;
  const int quad = lane >> 4, m = lane & 15;
  const int i0 = it * 16, n0 = (ng * 4 + wv) * 16;
  const unsigned short* arow = featsb + (size_t)(i0 + m) * 2688;
  const unsigned short* brow = woT + (size_t)(n0 + m) * 2688;
  f32x4 acc = (f32x4){0.f, 0.f, 0.f, 0.f};
#pragma unroll 4
  for (int s = 0; s < 84; s++) {
    const int ko = s * 32 + quad * 8;
    short8 af = *(const short8*)(arow + ko);
    short8 bf = *(const short8*)(brow + ko);
    acc = __builtin_amdgcn_mfma_f32_16x16x32_bf16(af, bf, acc, 0, 0, 0);
  }
  const float bias = bo[n0 + m];
#pragma unroll
  for (int r = 0; r < 4; r++)
    out[(size_t)(i0 + quad * 4 + r) * 384 + n0 + m] = acc[r] + bias;
}

extern "C" void kernel_launch(void* const* d_in, const int* in_sizes, int n_in,
                              void* d_out, int out_size, void* d_ws, size_t ws_size,
                              hipStream_t stream) {
  const float* s     = (const float*)d_in[0];
  const float* z     = (const float*)d_in[1];
  const float* rot   = (const float*)d_in[2];
  const float* trans = (const float*)d_in[3];
  const float* mask  = (const float*)d_in[4];
  const float* wq    = (const float*)d_in[5];
  const float* bq    = (const float*)d_in[6];
  const float* wkv   = (const float*)d_in[7];
  const float* bkv   = (const float*)d_in[8];
  const float* wqp   = (const float*)d_in[9];
  const float* bqp   = (const float*)d_in[10];
  const float* wkvp  = (const float*)d_in[11];
  const float* bkvp  = (const float*)d_in[12];
  const float* wb    = (const float*)d_in[13];
  const float* bb    = (const float*)d_in[14];
  const float* wz    = (const float*)d_in[15];
  const float* bz    = (const float*)d_in[16];
  const float* hwp   = (const float*)d_in[17];
  const float* wo    = (const float*)d_in[18];
  const float* bo    = (const float*)d_in[19];
  float* out = (float*)d_out;

  float* ws = (float*)d_ws;
  unsigned short* qbh   = (unsigned short*)(ws + OFF_QBH);
  unsigned short* kbh   = (unsigned short*)(ws + OFF_KBH);
  float* vb      = ws + OFF_VB;
  float* qpraw   = ws + OFF_QPRAW;
  float* kvpraw  = ws + OFF_KVPRAW;
  unsigned short* bbias_tb = (unsigned short*)(ws + OFF_BBIAS);
  unsigned short* pairzT   = (unsigned short*)(ws + OFF_PAIRZT);
  unsigned short* attnh    = (unsigned short*)(ws + OFF_ATTNH);
  unsigned short* featsb   = (unsigned short*)(ws + OFF_FEATSB);
  unsigned short* wT    = (unsigned short*)(ws + OFF_WCAT);
  unsigned short* wTall = (unsigned short*)(ws + OFF_WTALL);
  unsigned short* vptT  = (unsigned short*)(ws + OFF_VPT);
  unsigned short* woT   = (unsigned short*)(ws + OFF_WOT);
  unsigned short* qptH  = (unsigned short*)(ws + OFF_QPTH);
  unsigned short* qptL  = (unsigned short*)(ws + OFF_QPTL);
  unsigned short* kptH  = (unsigned short*)(ws + OFF_KPTH);
  unsigned short* kptL  = (unsigned short*)(ws + OFF_KPTL);
  float* qp2g = ws + OFF_QP2;
  float* kp2g = ws + OFF_KP2;
  unsigned short* sbf = (unsigned short*)(ws + OFF_SBF);

  prep_all<<<1014, 256, 0, stream>>>(wq, wkv, wqp, wkvp, wo, wb, wz, s,
                                     wTall, woT, wT, sbf);
  mega1<<<1880, 256, 0, stream>>>(z, wT, bb, bz, bbias_tb, pairzT,
                                  sbf, wTall, bq, bkv, bqp, bkvp,
                                  qbh, kbh, vb, qpraw, kvpraw);
  mega2<<<336, 256, 0, stream>>>(vb, qpraw, kvpraw, rot, trans, vptT,
                                 qptH, qptL, kptH, kptL, qp2g, kp2g);
  logits_fused<<<dim3(32, 8), 512, 0, stream>>>(qbh, kbh, qptH, qptL, kptH, kptL,
                                                qp2g, kp2g, bbias_tb, mask, hwp,
                                                vptT, rot, trans, attnh, featsb);
  o_pair_mfma<<<128, 256, 0, stream>>>(attnh, pairzT, featsb);
  out_mfma<<<dim3(32, 6), 256, 0, stream>>>(featsb, woT, bo, out);
}

// Round 7
// 323.209 us; speedup vs baseline: 1.0692x; 1.0692x over previous
//
#include <hip/hip_runtime.h>

// TranslationIPA: B=1, N=512, CS=384, CZ=128, H=8, C=256, PQ=8, PV=12
// feats layout: [o 2048 | x 96 | y 96 | z 96 | norm 96 | o_pair 256] = 2688

// workspace float offsets
#define OFF_QBH    0          // qbh  us[512*2048]
#define OFF_KBH    524288     // kbh  us[512*2048]
#define OFF_VB     1048576    // vb   f32[512*2048]
#define OFF_QPRAW  2097152    // f32[512*192]
#define OFF_KVPRAW 2195456    // f32[512*480]
#define OFF_BBIAS  2785280    // us[8*262144]  ([h][i*512+j] bf16)
#define OFF_PAIRZT 3833856    // us[512*32*512] ([i][d][j] bf16)
#define OFF_ATTNH  8028160    // us[8*512*512] ([h][i][j] bf16)
#define OFF_FEATSB 9076736    // us[512*2688] bf16
#define OFF_WCAT   9764864    // us[48*128]
#define OFF_WTALL  9767936    // us[6848*384]
#define OFF_VPT    11082752   // us[8*352*512]
#define OFF_WOT    11803648   // us[384*2688]
#define OFF_QPTH   12319744   // us[8*512*32]
#define OFF_QPTL   12385280   // us[8*512*32]
#define OFF_KPTH   12450816   // us[8*512*32]
#define OFF_KPTL   12516352   // us[8*512*32]
#define OFF_QP2    12581888   // f32[8*512]
#define OFF_KP2    12585984   // f32[8*512]
#define OFF_SBF    12590080   // us[512*384] bf16 copy of s

typedef __attribute__((ext_vector_type(8))) short short8;   // 8 bf16
typedef __attribute__((ext_vector_type(4))) float f32x4;

__device__ __forceinline__ unsigned short f2bf(float f) {   // RNE f32 -> bf16
  union { float f; unsigned u; } v; v.f = f;
  unsigned u = v.u;
  unsigned r = (u + 0x7fffu + ((u >> 16) & 1u)) >> 16;
  return (unsigned short)r;
}
__device__ __forceinline__ float bf2f(unsigned short h) {
  union { unsigned u; float f; } v; v.u = ((unsigned)h) << 16; return v.f;
}
__device__ __forceinline__ short8 pack8(float4 a, float4 b) {
  short8 r;
  r[0] = (short)f2bf(a.x); r[1] = (short)f2bf(a.y);
  r[2] = (short)f2bf(a.z); r[3] = (short)f2bf(a.w);
  r[4] = (short)f2bf(b.x); r[5] = (short)f2bf(b.y);
  r[6] = (short)f2bf(b.z); r[7] = (short)f2bf(b.w);
  return r;
}
// async global->LDS 16B per lane (dest = wave-uniform base + lane*16)
__device__ __forceinline__ void gl_lds16(const float* g, float* l) {
  __builtin_amdgcn_global_load_lds(
      (const __attribute__((address_space(1))) unsigned int*)(g),
      (__attribute__((address_space(3))) unsigned int*)(l), 16, 0, 0);
}

// ---------------- prep_all: all weight transposes + s->bf16, one launch -------------
__global__ __launch_bounds__(256) void prep_all(
    const float* __restrict__ wq, const float* __restrict__ wkv,
    const float* __restrict__ wqp, const float* __restrict__ wkvp,
    const float* __restrict__ wo, const float* __restrict__ wb,
    const float* __restrict__ wz, const float* __restrict__ s,
    unsigned short* __restrict__ wTall, unsigned short* __restrict__ woT,
    unsigned short* __restrict__ wT, unsigned short* __restrict__ sbf) {
  __shared__ float tile[64][65];
  const int b = blockIdx.x, t = threadIdx.x;
  if (b < 642) {
    const int ntile = b % 107, kt = b / 107;
    const float* src; int Nsrc, nloc0;
    const int ng0 = ntile * 64;
    if (ntile < 32)      { src = wq;   Nsrc = 2048; nloc0 = ng0; }
    else if (ntile < 96) { src = wkv;  Nsrc = 4096; nloc0 = ng0 - 2048; }
    else if (ntile < 99) { src = wqp;  Nsrc = 192;  nloc0 = ng0 - 6144; }
    else                 { src = wkvp; Nsrc = 480;  nloc0 = ng0 - 6336; }
    const int r = t >> 2, cs = (t & 3) * 16;
#pragma unroll
    for (int i = 0; i < 16; i += 4) {
      int n = nloc0 + cs + i;
      float4 v;
      if (n + 3 < Nsrc) v = *(const float4*)(src + (size_t)(kt * 64 + r) * Nsrc + n);
      else {
        v.x = (n + 0 < Nsrc) ? src[(size_t)(kt * 64 + r) * Nsrc + n + 0] : 0.f;
        v.y = (n + 1 < Nsrc) ? src[(size_t)(kt * 64 + r) * Nsrc + n + 1] : 0.f;
        v.z = (n + 2 < Nsrc) ? src[(size_t)(kt * 64 + r) * Nsrc + n + 2] : 0.f;
        v.w = (n + 3 < Nsrc) ? src[(size_t)(kt * 64 + r) * Nsrc + n + 3] : 0.f;
      }
      tile[r][cs + i + 0] = v.x; tile[r][cs + i + 1] = v.y;
      tile[r][cs + i + 2] = v.z; tile[r][cs + i + 3] = v.w;
    }
    __syncthreads();
    const int nr = t >> 2, ks = (t & 3) * 16;
    unsigned short ov[16];
#pragma unroll
    for (int i = 0; i < 16; i++) ov[i] = f2bf(tile[ks + i][nr]);
    unsigned short* dst = wTall + (size_t)(ng0 + nr) * 384 + kt * 64 + ks;
    *(uint4*)(dst) = *(const uint4*)&ov[0];
    *(uint4*)(dst + 8) = *(const uint4*)&ov[8];
  } else if (b < 894) {
    const int idx = b - 642;
    const int kt = idx % 42, ntile = idx / 42;
    const int r = t >> 2, cs = (t & 3) * 16;
#pragma unroll
    for (int i = 0; i < 16; i += 4) {
      float4 v = *(const float4*)(wo + (size_t)(kt * 64 + r) * 384 + ntile * 64 + cs + i);
      tile[r][cs + i + 0] = v.x; tile[r][cs + i + 1] = v.y;
      tile[r][cs + i + 2] = v.z; tile[r][cs + i + 3] = v.w;
    }
    __syncthreads();
    const int nr = t >> 2, ks = (t & 3) * 16;
    unsigned short ov[16];
#pragma unroll
    for (int i = 0; i < 16; i++) ov[i] = f2bf(tile[ks + i][nr]);
    unsigned short* dst = woT + (size_t)(ntile * 64 + nr) * 2688 + kt * 64 + ks;
    *(uint4*)(dst) = *(const uint4*)&ov[0];
    *(uint4*)(dst + 8) = *(const uint4*)&ov[8];
  } else if (b < 918) {
    const int l = (b - 894) * 256 + t;  // 48*128 = 6144
    if (l < 6144) {
      int n = l >> 7, k = l & 127;
      float v = (n < 8) ? wb[k * 8 + n] * 0.5773502691896258f
                        : (n < 40 ? wz[k * 32 + (n - 8)] : 0.f);
      wT[l] = f2bf(v);
    }
  } else {
    const int gid = (b - 918) * 256 + t;       // 24576 threads x 8 elems
    const int off = gid * 8;                   // covers 512*384 = 196608
    float4 a0 = *(const float4*)(s + off);
    float4 a1 = *(const float4*)(s + off + 4);
    *(short8*)(sbf + off) = pack8(a0, a1);
  }
}

// ---------------- mega1: zpass (blocks [0,256)) U proj ([256,1112)) -----------------
// zpass: ping-pong LDS tile of 64 z-rows staged via async global_load_lds (prefetch
// tile T+1 during MFMA compute of tile T); wT B-frags in registers, amortized over
// 16 tiles/block. Fixes both the LDS-instr bound (r6) and load-latency bound (r2-r5).
__global__ __launch_bounds__(256) void mega1(
    const float* __restrict__ z, const unsigned short* __restrict__ wT,
    const float* __restrict__ bb, const float* __restrict__ bz,
    unsigned short* __restrict__ bbias_tb, unsigned short* __restrict__ pairzT,
    const unsigned short* __restrict__ sbf, const unsigned short* __restrict__ wTall,
    const float* __restrict__ bq, const float* __restrict__ bkv,
    const float* __restrict__ bqp, const float* __restrict__ bkvp,
    unsigned short* __restrict__ qbh, unsigned short* __restrict__ kbh,
    float* __restrict__ vb, float* __restrict__ qpraw, float* __restrict__ kvpraw) {
  const int lane = threadIdx.x & 63, wv = threadIdx.x >> 6;
  const int quad = lane >> 4, m = lane & 15;
  if (blockIdx.x < 256) {
    // ------- zpass: 16 tiles x 64 rows per block, double-buffered LDS -------
    __shared__ __align__(16) float zt[2][64][128];
    __shared__ __align__(16) unsigned short lb[4][8][16];
    __shared__ __align__(16) unsigned short lp[4][32][16];
    short8 bfw[3][4];
#pragma unroll
    for (int nt = 0; nt < 3; nt++)
#pragma unroll
      for (int s = 0; s < 4; s++)
        bfw[nt][s] = *(const short8*)(wT + (size_t)(nt * 16 + m) * 128 + s * 32 + quad * 8);
    float bias[3];
#pragma unroll
    for (int nt = 0; nt < 3; nt++) {
      int c = nt * 16 + m;
      bias[nt] = (c < 8) ? 0.5773502691896258f * bb[c] : (c < 40 ? bz[c - 8] : 0.f);
    }
    const int lrow = lane >> 5, lcol = (lane & 31) * 4;   // staging lane mapping
    // prologue: stage tile 0
    {
      const int Tg0 = blockIdx.x * 16;
#pragma unroll
      for (int i2 = 0; i2 < 8; i2++) {
        const int k = wv * 8 + i2;
        gl_lds16(z + (size_t)(Tg0 * 64 + 2 * k + lrow) * 128 + lcol, &zt[0][2 * k][0]);
      }
    }
    __syncthreads();                      // drains vmcnt -> tile 0 resident
    for (int T = 0; T < 16; T++) {
      const int buf = T & 1;
      const int Tg = blockIdx.x * 16 + T;
      if (T < 15) {                       // async prefetch tile T+1 into buf^1
#pragma unroll
        for (int i2 = 0; i2 < 8; i2++) {
          const int k = wv * 8 + i2;
          gl_lds16(z + (size_t)((Tg + 1) * 64 + 2 * k + lrow) * 128 + lcol,
                   &zt[buf ^ 1][2 * k][0]);
        }
      }
      // compute tile T from LDS
      f32x4 acc[3];
#pragma unroll
      for (int nt = 0; nt < 3; nt++) acc[nt] = (f32x4){0.f, 0.f, 0.f, 0.f};
#pragma unroll
      for (int s = 0; s < 4; s++) {
        const float* zr = &zt[buf][wv * 16 + m][s * 32 + quad * 8];
        float4 a0 = *(const float4*)(zr);
        float4 a1 = *(const float4*)(zr + 4);
        short8 af = pack8(a0, a1);
#pragma unroll
        for (int nt = 0; nt < 3; nt++)
          acc[nt] = __builtin_amdgcn_mfma_f32_16x16x32_bf16(af, bfw[nt][s], acc[nt], 0, 0, 0);
      }
#pragma unroll
      for (int nt = 0; nt < 3; nt++) {
        const int c = nt * 16 + m;
#pragma unroll
        for (int r = 0; r < 4; r++) {
          const float v = acc[nt][r] + bias[nt];
          const int jl = quad * 4 + r;
          if (c < 8)       lb[wv][c][jl] = f2bf(v);
          else if (c < 40) lp[wv][c - 8][jl] = f2bf(v);
        }
      }
      const int row0 = Tg * 64 + wv * 16;
      const int i = row0 >> 9, j0 = row0 & 511;
      if (lane < 16) {
        int c = lane >> 1, half = lane & 1;
        uint4 val = *(const uint4*)&lb[wv][c][half * 8];
        *(uint4*)(bbias_tb + (size_t)c * 262144 + row0 + half * 8) = val;
      }
      {
        int d = lane >> 1, half = lane & 1;
        uint4 val = *(const uint4*)&lp[wv][d][half * 8];
        *(uint4*)(pairzT + ((size_t)i * 32 + d) * 512 + j0 + half * 8) = val;
      }
      __syncthreads();                    // drain prefetch + all waves done with buf
    }
  } else {
    // ------- proj -------
    const int b2 = blockIdx.x - 256;
    const int bx = b2 % 107, row0 = (b2 / 107) * 64;
    const int n0 = bx * 64;
    const unsigned short* srow = sbf + (size_t)(row0 + wv * 16 + m) * 384;
    f32x4 acc[4];
#pragma unroll
    for (int nt = 0; nt < 4; nt++) acc[nt] = (f32x4){0.f, 0.f, 0.f, 0.f};
#pragma unroll
    for (int ksx = 0; ksx < 12; ksx++) {
      const int c0 = ksx * 32 + quad * 8;
      short8 af = *(const short8*)(srow + c0);
#pragma unroll
      for (int nt = 0; nt < 4; nt++) {
        short8 bfw2 = *(const short8*)(wTall + (size_t)(n0 + nt * 16 + m) * 384 + c0);
        acc[nt] = __builtin_amdgcn_mfma_f32_16x16x32_bf16(af, bfw2, acc[nt], 0, 0, 0);
      }
    }
    const int rbase = row0 + wv * 16 + quad * 4;
#pragma unroll
    for (int nt = 0; nt < 4; nt++) {
      const int col = n0 + nt * 16 + m;
      if (n0 < 2048) {
        const float bias = bq[col];
#pragma unroll
        for (int r = 0; r < 4; r++)
          qbh[(size_t)(rbase + r) * 2048 + col] = f2bf(acc[nt][r] + bias);
      } else if (n0 < 6144) {
        const int ckv = col - 2048;
        const float bias = bkv[ckv];
        const int hh = ckv >> 9, c = ckv & 511;
        if (c < 256) {
#pragma unroll
          for (int r = 0; r < 4; r++)
            kbh[(size_t)(rbase + r) * 2048 + hh * 256 + c] = f2bf(acc[nt][r] + bias);
        } else {
#pragma unroll
          for (int r = 0; r < 4; r++)
            vb[(size_t)(rbase + r) * 2048 + hh * 256 + (c - 256)] = acc[nt][r] + bias;
        }
      } else if (n0 < 6336) {
        const int cq = col - 6144;
        const float bias = bqp[cq];
#pragma unroll
        for (int r = 0; r < 4; r++)
          qpraw[(size_t)(rbase + r) * 192 + cq] = acc[nt][r] + bias;
      } else {
        const int ck = col - 6336;
        if (ck < 480) {
          const float bias = bkvp[ck];
#pragma unroll
          for (int r = 0; r < 4; r++)
            kvpraw[(size_t)(rbase + r) * 480 + ck] = acc[nt][r] + bias;
        }
      }
    }
  }
}

// ---------------- mega2: vpt_prep (blocks [0,320)) U pts_planes ([320,336)) ---------
__global__ __launch_bounds__(256) void mega2(
    const float* __restrict__ vb, const float* __restrict__ qpraw,
    const float* __restrict__ kvpraw, const float* __restrict__ rot,
    const float* __restrict__ trans, unsigned short* __restrict__ vptT,
    unsigned short* __restrict__ qptH, unsigned short* __restrict__ qptL,
    unsigned short* __restrict__ kptH, unsigned short* __restrict__ kptL,
    float* __restrict__ qp2g, float* __restrict__ kp2g) {
  __shared__ float tile[64][65];
  const int b = blockIdx.x, t = threadIdx.x;
  if (b < 320) {
    const int jt = b & 7, h = (b >> 3) & 7, part = b >> 6;
    const int j0 = jt * 64;
    if (part < 4) {
      const int c0 = part * 64;
      const int r = t >> 2, cs = (t & 3) * 16;
#pragma unroll
      for (int ii = 0; ii < 16; ii += 4) {
        float4 v = *(const float4*)(vb + (size_t)(j0 + r) * 2048 + h * 256 + c0 + cs + ii);
        tile[r][cs + ii + 0] = v.x; tile[r][cs + ii + 1] = v.y;
        tile[r][cs + ii + 2] = v.z; tile[r][cs + ii + 3] = v.w;
      }
      __syncthreads();
      const int cl = t >> 2, js = (t & 3) * 16;
      unsigned short ov[16];
#pragma unroll
      for (int x = 0; x < 16; x++) ov[x] = f2bf(tile[js + x][cl]);
      unsigned short* dst = vptT + ((size_t)h * 352 + c0 + cl) * 512 + j0 + js;
      *(uint4*)dst = *(const uint4*)&ov[0];
      *(uint4*)(dst + 8) = *(const uint4*)&ov[8];
    } else {
      float (*lds)[37] = (float(*)[37])&tile[0][0];   // 64 x 37 view
      for (int l = t; l < 64 * 36; l += 256) {
        int jl = l / 36, w = l % 36;
        int p = w / 3, d = w % 3;
        const int n = j0 + jl;
        const int pidx = h * 20 + 8 + p;
        const float* kr = kvpraw + (size_t)n * 480;
        float px = kr[pidx], py = kr[160 + pidx], pz = kr[320 + pidx];
        const float* R = rot + n * 9;
        lds[jl][w] = R[d * 3 + 0] * px + R[d * 3 + 1] * py + R[d * 3 + 2] * pz + trans[n * 3 + d];
      }
      __syncthreads();
#pragma unroll
      for (int step = 0; step < 3; step++) {
        int chunk = t + 256 * step;          // < 768 = 96 rows x 8 chunks
        int row = chunk >> 3, js = (chunk & 7) * 8;
        unsigned short ov[8];
#pragma unroll
        for (int x = 0; x < 8; x++) {
          int w = (row < 48) ? row : row - 48;
          float f = (w < 36) ? lds[js + x][w] : 0.f;
          unsigned short hi = f2bf(f);
          ov[x] = (row < 48) ? hi : f2bf(f - bf2f(hi));
        }
        *(uint4*)(vptT + ((size_t)h * 352 + 256 + row) * 512 + j0 + js) = *(const uint4*)&ov[0];
      }
    }
  } else {
    // ------- pts_planes with inline rigid -------
    const int idx = b - 320;
    const int row = (idx & 1) * 256 + t;
    const int h = idx >> 1;
    const float* R  = rot + row * 9;
    const float* tr = trans + row * 3;
    {
      const float* qr = qpraw + (size_t)row * 192;
      unsigned short hi[32], lo[32]; float s2 = 0.f;
#pragma unroll
      for (int p = 0; p < 8; p++) {
        const int pidx = h * 8 + p;
        float px = qr[pidx], py = qr[64 + pidx], pz = qr[128 + pidx];
        float X = R[0] * px + R[1] * py + R[2] * pz + tr[0];
        float Y = R[3] * px + R[4] * py + R[5] * pz + tr[1];
        float Z = R[6] * px + R[7] * py + R[8] * pz + tr[2];
        hi[p * 3 + 0] = f2bf(X); lo[p * 3 + 0] = f2bf(X - bf2f(hi[p * 3 + 0]));
        hi[p * 3 + 1] = f2bf(Y); lo[p * 3 + 1] = f2bf(Y - bf2f(hi[p * 3 + 1]));
        hi[p * 3 + 2] = f2bf(Z); lo[p * 3 + 2] = f2bf(Z - bf2f(hi[p * 3 + 2]));
        s2 += X * X + Y * Y + Z * Z;
      }
#pragma unroll
      for (int w = 24; w < 32; w++) { hi[w] = 0; lo[w] = 0; }
      unsigned short* dh = qptH + ((size_t)h * 512 + row) * 32;
      unsigned short* dl = qptL + ((size_t)h * 512 + row) * 32;
#pragma unroll
      for (int g = 0; g < 4; g++) {
        *(uint4*)(dh + g * 8) = *(const uint4*)&hi[g * 8];
        *(uint4*)(dl + g * 8) = *(const uint4*)&lo[g * 8];
      }
      qp2g[h * 512 + row] = s2;
    }
    {
      const float* kr = kvpraw + (size_t)row * 480;
      unsigned short hi[32], lo[32]; float s2 = 0.f;
#pragma unroll
      for (int p = 0; p < 8; p++) {
        const int pidx = h * 20 + p;
        float px = kr[pidx], py = kr[160 + pidx], pz = kr[320 + pidx];
        float X = R[0] * px + R[1] * py + R[2] * pz + tr[0];
        float Y = R[3] * px + R[4] * py + R[5] * pz + tr[1];
        float Z = R[6] * px + R[7] * py + R[8] * pz + tr[2];
        hi[p * 3 + 0] = f2bf(X); lo[p * 3 + 0] = f2bf(X - bf2f(hi[p * 3 + 0]));
        hi[p * 3 + 1] = f2bf(Y); lo[p * 3 + 1] = f2bf(Y - bf2f(hi[p * 3 + 1]));
        hi[p * 3 + 2] = f2bf(Z); lo[p * 3 + 2] = f2bf(Z - bf2f(hi[p * 3 + 2]));
        s2 += X * X + Y * Y + Z * Z;
      }
#pragma unroll
      for (int w = 24; w < 32; w++) { hi[w] = 0; lo[w] = 0; }
      unsigned short* dh = kptH + ((size_t)h * 512 + row) * 32;
      unsigned short* dl = kptL + ((size_t)h * 512 + row) * 32;
#pragma unroll
      for (int g = 0; g < 4; g++) {
        *(uint4*)(dh + g * 8) = *(const uint4*)&hi[g * 8];
        *(uint4*)(dl + g * 8) = *(const uint4*)&lo[g * 8];
      }
      kp2g[h * 512 + row] = s2;
    }
  }
}

// ---------------- fused logits + softmax + a@[v,pts], 8 waves ------------------------
__global__ __launch_bounds__(512) void logits_fused(
    const unsigned short* __restrict__ qbh, const unsigned short* __restrict__ kbh,
    const unsigned short* __restrict__ qptH, const unsigned short* __restrict__ qptL,
    const unsigned short* __restrict__ kptH, const unsigned short* __restrict__ kptL,
    const float* __restrict__ qp2g, const float* __restrict__ kp2g,
    const unsigned short* __restrict__ bbias_tb, const float* __restrict__ mask,
    const float* __restrict__ hwp, const unsigned short* __restrict__ vptT,
    const float* __restrict__ rot, const float* __restrict__ trans,
    unsigned short* __restrict__ attnh, unsigned short* __restrict__ featsb) {
  const int it = blockIdx.x, h = blockIdx.y;
  const int i0 = it * 16;
  __shared__ __align__(16) unsigned short sth[8][16][72], stl[8][16][72];
  __shared__ float redm[16][8], reds[16][8];
  __shared__ float lds_h[16][48], lds_l[16][48];
  const int t = threadIdx.x;
  const int lane = t & 63, wv = t >> 6;
  const int quad = lane >> 4, m = lane & 15;
  const int jw0 = wv * 64;

  // ---- QK^T (4 n-tiles of 16 j each) ----
  f32x4 acc[4];
#pragma unroll
  for (int nt = 0; nt < 4; nt++) acc[nt] = (f32x4){0.f, 0.f, 0.f, 0.f};
  const unsigned short* qrow = qbh + (size_t)(i0 + m) * 2048 + h * 256;
#pragma unroll
  for (int s = 0; s < 8; s++) {
    short8 af = *(const short8*)(qrow + s * 32 + quad * 8);
#pragma unroll
    for (int nt = 0; nt < 4; nt++) {
      short8 bfr = *(const short8*)(kbh + (size_t)(jw0 + nt * 16 + m) * 2048 + h * 256 + s * 32 + quad * 8);
      acc[nt] = __builtin_amdgcn_mfma_f32_16x16x32_bf16(af, bfr, acc[nt], 0, 0, 0);
    }
  }

  // ---- point cross-term (hi/lo split) from global planes ----
  short8 aqh = *(const short8*)(qptH + ((size_t)h * 512 + i0 + m) * 32 + quad * 8);
  short8 aql = *(const short8*)(qptL + ((size_t)h * 512 + i0 + m) * 32 + quad * 8);
  f32x4 accp[4];
#pragma unroll
  for (int nt = 0; nt < 4; nt++) {
    const size_t krow = ((size_t)h * 512 + jw0 + nt * 16 + m) * 32 + quad * 8;
    short8 bkh = *(const short8*)(kptH + krow);
    short8 bkl = *(const short8*)(kptL + krow);
    f32x4 p = (f32x4){0.f, 0.f, 0.f, 0.f};
    p = __builtin_amdgcn_mfma_f32_16x16x32_bf16(aqh, bkh, p, 0, 0, 0);
    p = __builtin_amdgcn_mfma_f32_16x16x32_bf16(aqh, bkl, p, 0, 0, 0);
    p = __builtin_amdgcn_mfma_f32_16x16x32_bf16(aql, bkh, p, 0, 0, 0);
    accp[nt] = p;
  }

  // ---- logits ----
  const float c1 = 0.03608439182435161f;                         // 1/sqrt(768)
  const float hw = log1pf(expf(hwp[h])) * 0.09622504486493764f;  // softplus*sqrt(1/108)
  float qp2v[4];
#pragma unroll
  for (int r = 0; r < 4; r++) qp2v[r] = qp2g[h * 512 + i0 + quad * 4 + r];
  float lg[4][4];
  float rmax[4] = {-1e30f, -1e30f, -1e30f, -1e30f};
#pragma unroll
  for (int nt = 0; nt < 4; nt++) {
    const int j = jw0 + nt * 16 + m;
    const float kp2v = kp2g[h * 512 + j];
    const float mj = mask[j];
#pragma unroll
    for (int r = 0; r < 4; r++) {
      const int il = quad * 4 + r;
      const float pt = qp2v[r] + kp2v - 2.f * accp[nt][r];
      float v = c1 * acc[nt][r]
              + bf2f(bbias_tb[(size_t)h * 262144 + (size_t)(i0 + il) * 512 + j])
              - 0.5f * hw * pt
              + 100000.f * (mask[i0 + il] * mj - 1.f);
      lg[nt][r] = v;
      rmax[r] = fmaxf(rmax[r], v);
    }
  }
  // ---- softmax (cross-lane within 16-lane group, then cross-wave via LDS) ----
#pragma unroll
  for (int r = 0; r < 4; r++) {
#pragma unroll
    for (int off = 1; off < 16; off <<= 1) rmax[r] = fmaxf(rmax[r], __shfl_xor(rmax[r], off));
  }
  if (m == 0) {
#pragma unroll
    for (int r = 0; r < 4; r++) redm[quad * 4 + r][wv] = rmax[r];
  }
  __syncthreads();
  float rowm[4], rsum[4];
#pragma unroll
  for (int r = 0; r < 4; r++) {
    const int il = quad * 4 + r;
    float m0 = fmaxf(fmaxf(redm[il][0], redm[il][1]), fmaxf(redm[il][2], redm[il][3]));
    float m1 = fmaxf(fmaxf(redm[il][4], redm[il][5]), fmaxf(redm[il][6], redm[il][7]));
    rowm[r] = fmaxf(m0, m1);
    rsum[r] = 0.f;
  }
#pragma unroll
  for (int nt = 0; nt < 4; nt++)
#pragma unroll
    for (int r = 0; r < 4; r++) {
      float e = __expf(lg[nt][r] - rowm[r]);
      lg[nt][r] = e;
      rsum[r] += e;
    }
#pragma unroll
  for (int r = 0; r < 4; r++) {
#pragma unroll
    for (int off = 1; off < 16; off <<= 1) rsum[r] += __shfl_xor(rsum[r], off);
  }
  if (m == 0) {
#pragma unroll
    for (int r = 0; r < 4; r++) reds[quad * 4 + r][wv] = rsum[r];
  }
  __syncthreads();
  float inv[4];
#pragma unroll
  for (int r = 0; r < 4; r++) {
    const int il = quad * 4 + r;
    float s0 = (reds[il][0] + reds[il][1]) + (reds[il][2] + reds[il][3]);
    float s1 = (reds[il][4] + reds[il][5]) + (reds[il][6] + reds[il][7]);
    inv[r] = 1.f / (s0 + s1);
  }
  // ---- a -> bf16 hi/lo into LDS ----
#pragma unroll
  for (int nt = 0; nt < 4; nt++)
#pragma unroll
    for (int r = 0; r < 4; r++) {
      const int il = quad * 4 + r;
      float a = lg[nt][r] * inv[r];
      unsigned short hi = f2bf(a);
      sth[wv][il][nt * 16 + m] = hi;
      stl[wv][il][nt * 16 + m] = f2bf(a - bf2f(hi));
    }
  __syncthreads();
  // attnh global (hi only, for o_pair), coalesced: 16 rows x 8 segs of 8 per wave
#pragma unroll
  for (int step = 0; step < 2; step++) {
    const int idx = lane + 64 * step;        // 0..127
    const int il = idx >> 3, seg = idx & 7;
    uint4 vh = *(const uint4*)&sth[wv][il][seg * 8];
    *(uint4*)(attnh + ((size_t)h * 512 + i0 + il) * 512 + jw0 + seg * 8) = vh;
  }

  // ---- phase 2: a @ vptT (A-frags from LDS across all 8 j-slices) ----
  const int nt0 = (wv < 6) ? wv * 3 : 18 + (wv - 6) * 2;
  const int ncnt = (wv < 6) ? 3 : 2;
  f32x4 vacc[3];
#pragma unroll
  for (int k = 0; k < 3; k++) vacc[k] = (f32x4){0.f, 0.f, 0.f, 0.f};
  const unsigned short* vbase = vptT + (size_t)h * 352 * 512;
#pragma unroll
  for (int s = 0; s < 16; s++) {
    const int wsrc = s >> 1, col = (s & 1) * 32 + quad * 8;
    short8 ah = *(const short8*)&sth[wsrc][m][col];
    short8 al = *(const short8*)&stl[wsrc][m][col];
    const int ko = s * 32 + quad * 8;
#pragma unroll
    for (int k = 0; k < 3; k++) {
      if (k < ncnt) {
        const int nt = nt0 + k;
        short8 bfr = *(const short8*)(vbase + (size_t)(nt * 16 + m) * 512 + ko);
        vacc[k] = __builtin_amdgcn_mfma_f32_16x16x32_bf16(ah, bfr, vacc[k], 0, 0, 0);
        if (nt >= 16 && nt < 19)
          vacc[k] = __builtin_amdgcn_mfma_f32_16x16x32_bf16(al, bfr, vacc[k], 0, 0, 0);
      }
    }
  }
#pragma unroll
  for (int k = 0; k < 3; k++) {
    if (k < ncnt) {
      const int nt = nt0 + k;
      if (nt < 16) {
#pragma unroll
        for (int r = 0; r < 4; r++)
          featsb[(size_t)(i0 + quad * 4 + r) * 2688 + h * 256 + nt * 16 + m] = f2bf(vacc[k][r]);
      } else if (nt < 19) {
        const int w = (nt - 16) * 16 + m;
#pragma unroll
        for (int r = 0; r < 4; r++) if (w < 36) lds_h[quad * 4 + r][w] = vacc[k][r];
      } else {
        const int w = (nt - 19) * 16 + m;
#pragma unroll
        for (int r = 0; r < 4; r++) if (w < 36) lds_l[quad * 4 + r][w] = vacc[k][r];
      }
    }
  }
  __syncthreads();
  if (t < 192) {
    const int il = t / 12, p = t % 12, irow = i0 + il;
    const float* R = rot + irow * 9;
    const float* tr = trans + irow * 3;
    float x  = lds_h[il][p * 3 + 0] + lds_l[il][p * 3 + 0] - tr[0];
    float y  = lds_h[il][p * 3 + 1] + lds_l[il][p * 3 + 1] - tr[1];
    float zz = lds_h[il][p * 3 + 2] + lds_l[il][p * 3 + 2] - tr[2];
    float o0 = R[0] * x + R[3] * y + R[6] * zz;   // R^T v
    float o1 = R[1] * x + R[4] * y + R[7] * zz;
    float o2 = R[2] * x + R[5] * y + R[8] * zz;
    float nrm = sqrtf(o0 * o0 + o1 * o1 + o2 * o2 + 1e-8f);
    unsigned short* fr = featsb + (size_t)irow * 2688 + 2048;
    fr[h * 12 + p]       = f2bf(o0);
    fr[96 + h * 12 + p]  = f2bf(o1);
    fr[192 + h * 12 + p] = f2bf(o2);
    fr[288 + h * 12 + p] = f2bf(nrm);
  }
}

// ---------------- o_pair via MFMA: per-i [8h x 512j] @ [512j x 32d] ------------------
__global__ __launch_bounds__(256) void o_pair_mfma(
    const unsigned short* __restrict__ attnh, const unsigned short* __restrict__ pairzT,
    unsigned short* __restrict__ featsb) {
  const int lane = threadIdx.x & 63, wv = threadIdx.x >> 6;
  const int quad = lane >> 4, m = lane & 15;
  const int i = blockIdx.x * 4 + wv;          // grid 128
  f32x4 acc[2];
  acc[0] = (f32x4){0.f, 0.f, 0.f, 0.f};
  acc[1] = (f32x4){0.f, 0.f, 0.f, 0.f};
#pragma unroll
  for (int s = 0; s < 16; s++) {
    const int ko = s * 32 + quad * 8;
    short8 af = *(const short8*)(attnh + (size_t)(m & 7) * 262144 + (size_t)i * 512 + ko);
#pragma unroll
    for (int nt = 0; nt < 2; nt++) {
      short8 bfr = *(const short8*)(pairzT + ((size_t)i * 32 + nt * 16 + m) * 512 + ko);
      acc[nt] = __builtin_amdgcn_mfma_f32_16x16x32_bf16(af, bfr, acc[nt], 0, 0, 0);
    }
  }
  if (quad < 2) {
#pragma unroll
    for (int nt = 0; nt < 2; nt++)
#pragma unroll
      for (int r = 0; r < 4; r++) {
        const int hh = quad * 4 + r, d = nt * 16 + m;
        featsb[(size_t)i * 2688 + 2432 + hh * 32 + d] = f2bf(acc[nt][r]);
      }
  }
}

// ---------------- out = featsb @ woT^T + bo via MFMA (no atomics) -------------------
__global__ __launch_bounds__(256) void out_mfma(
    const unsigned short* __restrict__ featsb, const unsigned short* __restrict__ woT,
    const float* __restrict__ bo, float* __restrict__ out) {
  const int it = blockIdx.x, ng = blockIdx.y;   // grid (32, 6)
  const int lane = threadIdx.x & 63, wv = threadIdx.x >> 6;
  const int quad = lane >> 4, m = lane & 15;
  const int i0 = it * 16, n0 = (ng * 4 + wv) * 16;
  const unsigned short* arow = featsb + (size_t)(i0 + m) * 2688;
  const unsigned short* brow = woT + (size_t)(n0 + m) * 2688;
  f32x4 acc = (f32x4){0.f, 0.f, 0.f, 0.f};
#pragma unroll 4
  for (int s = 0; s < 84; s++) {
    const int ko = s * 32 + quad * 8;
    short8 af = *(const short8*)(arow + ko);
    short8 bf = *(const short8*)(brow + ko);
    acc = __builtin_amdgcn_mfma_f32_16x16x32_bf16(af, bf, acc, 0, 0, 0);
  }
  const float bias = bo[n0 + m];
#pragma unroll
  for (int r = 0; r < 4; r++)
    out[(size_t)(i0 + quad * 4 + r) * 384 + n0 + m] = acc[r] + bias;
}

extern "C" void kernel_launch(void* const* d_in, const int* in_sizes, int n_in,
                              void* d_out, int out_size, void* d_ws, size_t ws_size,
                              hipStream_t stream) {
  const float* s     = (const float*)d_in[0];
  const float* z     = (const float*)d_in[1];
  const float* rot   = (const float*)d_in[2];
  const float* trans = (const float*)d_in[3];
  const float* mask  = (const float*)d_in[4];
  const float* wq    = (const float*)d_in[5];
  const float* bq    = (const float*)d_in[6];
  const float* wkv   = (const float*)d_in[7];
  const float* bkv   = (const float*)d_in[8];
  const float* wqp   = (const float*)d_in[9];
  const float* bqp   = (const float*)d_in[10];
  const float* wkvp  = (const float*)d_in[11];
  const float* bkvp  = (const float*)d_in[12];
  const float* wb    = (const float*)d_in[13];
  const float* bb    = (const float*)d_in[14];
  const float* wz    = (const float*)d_in[15];
  const float* bz    = (const float*)d_in[16];
  const float* hwp   = (const float*)d_in[17];
  const float* wo    = (const float*)d_in[18];
  const float* bo    = (const float*)d_in[19];
  float* out = (float*)d_out;

  float* ws = (float*)d_ws;
  unsigned short* qbh   = (unsigned short*)(ws + OFF_QBH);
  unsigned short* kbh   = (unsigned short*)(ws + OFF_KBH);
  float* vb      = ws + OFF_VB;
  float* qpraw   = ws + OFF_QPRAW;
  float* kvpraw  = ws + OFF_KVPRAW;
  unsigned short* bbias_tb = (unsigned short*)(ws + OFF_BBIAS);
  unsigned short* pairzT   = (unsigned short*)(ws + OFF_PAIRZT);
  unsigned short* attnh    = (unsigned short*)(ws + OFF_ATTNH);
  unsigned short* featsb   = (unsigned short*)(ws + OFF_FEATSB);
  unsigned short* wT    = (unsigned short*)(ws + OFF_WCAT);
  unsigned short* wTall = (unsigned short*)(ws + OFF_WTALL);
  unsigned short* vptT  = (unsigned short*)(ws + OFF_VPT);
  unsigned short* woT   = (unsigned short*)(ws + OFF_WOT);
  unsigned short* qptH  = (unsigned short*)(ws + OFF_QPTH);
  unsigned short* qptL  = (unsigned short*)(ws + OFF_QPTL);
  unsigned short* kptH  = (unsigned short*)(ws + OFF_KPTH);
  unsigned short* kptL  = (unsigned short*)(ws + OFF_KPTL);
  float* qp2g = ws + OFF_QP2;
  float* kp2g = ws + OFF_KP2;
  unsigned short* sbf = (unsigned short*)(ws + OFF_SBF);

  prep_all<<<1014, 256, 0, stream>>>(wq, wkv, wqp, wkvp, wo, wb, wz, s,
                                     wTall, woT, wT, sbf);
  mega1<<<1112, 256, 0, stream>>>(z, wT, bb, bz, bbias_tb, pairzT,
                                  sbf, wTall, bq, bkv, bqp, bkvp,
                                  qbh, kbh, vb, qpraw, kvpraw);
  mega2<<<336, 256, 0, stream>>>(vb, qpraw, kvpraw, rot, trans, vptT,
                                 qptH, qptL, kptH, kptL, qp2g, kp2g);
  logits_fused<<<dim3(32, 8), 512, 0, stream>>>(qbh, kbh, qptH, qptL, kptH, kptL,
                                                qp2g, kp2g, bbias_tb, mask, hwp,
                                                vptT, rot, trans, attnh, featsb);
  o_pair_mfma<<<128, 256, 0, stream>>>(attnh, pairzT, featsb);
  out_mfma<<<dim3(32, 6), 256, 0, stream>>>(featsb, woT, bo, out);
}

// Round 8
// 320.103 us; speedup vs baseline: 1.0795x; 1.0097x over previous
//
#include <hip/hip_runtime.h>

// TranslationIPA: B=1, N=512, CS=384, CZ=128, H=8, C=256, PQ=8, PV=12
// feats layout: [o 2048 | x 96 | y 96 | z 96 | norm 96 | o_pair 256] = 2688

// workspace float offsets
#define OFF_QBH    0          // qbh  us[512*2048]
#define OFF_KBH    524288     // kbh  us[512*2048]
#define OFF_VB     1048576    // vb   f32[512*2048]
#define OFF_QPRAW  2097152    // f32[512*192]
#define OFF_KVPRAW 2195456    // f32[512*480]
#define OFF_BBIAS  2785280    // us[8*262144]  ([h][i*512+j] bf16)
#define OFF_PAIRZT 3833856    // us[512*32*512] ([i][d][j] bf16)
#define OFF_ATTNH  8028160    // us[8*512*512] ([h][i][j] bf16)
#define OFF_FEATSB 9076736    // us[512*2688] bf16
#define OFF_WCAT   9764864    // us[48*128]
#define OFF_WTALL  9767936    // us[6848*384]
#define OFF_VPT    11082752   // us[8*352*512]
#define OFF_WOT    11803648   // us[384*2688]
#define OFF_QPTH   12319744   // us[8*512*32]
#define OFF_QPTL   12385280   // us[8*512*32]
#define OFF_KPTH   12450816   // us[8*512*32]
#define OFF_KPTL   12516352   // us[8*512*32]
#define OFF_QP2    12581888   // f32[8*512]
#define OFF_KP2    12585984   // f32[8*512]
#define OFF_SBF    12590080   // us[512*384] bf16 copy of s

typedef __attribute__((ext_vector_type(8))) short short8;   // 8 bf16
typedef __attribute__((ext_vector_type(4))) float f32x4;

__device__ __forceinline__ unsigned short f2bf(float f) {   // RNE f32 -> bf16
  union { float f; unsigned u; } v; v.f = f;
  unsigned u = v.u;
  unsigned r = (u + 0x7fffu + ((u >> 16) & 1u)) >> 16;
  return (unsigned short)r;
}
__device__ __forceinline__ float bf2f(unsigned short h) {
  union { unsigned u; float f; } v; v.u = ((unsigned)h) << 16; return v.f;
}
__device__ __forceinline__ short8 pack8(float4 a, float4 b) {
  short8 r;
  r[0] = (short)f2bf(a.x); r[1] = (short)f2bf(a.y);
  r[2] = (short)f2bf(a.z); r[3] = (short)f2bf(a.w);
  r[4] = (short)f2bf(b.x); r[5] = (short)f2bf(b.y);
  r[6] = (short)f2bf(b.z); r[7] = (short)f2bf(b.w);
  return r;
}
// async global->LDS 16B per lane (dest = wave-uniform base + lane*16)
__device__ __forceinline__ void gl_lds16(const float* g, float* l) {
  __builtin_amdgcn_global_load_lds(
      (const __attribute__((address_space(1))) unsigned int*)(g),
      (__attribute__((address_space(3))) unsigned int*)(l), 16, 0, 0);
}

// ---------------- prep_all: all weight transposes + s->bf16, one launch -------------
__global__ __launch_bounds__(256) void prep_all(
    const float* __restrict__ wq, const float* __restrict__ wkv,
    const float* __restrict__ wqp, const float* __restrict__ wkvp,
    const float* __restrict__ wo, const float* __restrict__ wb,
    const float* __restrict__ wz, const float* __restrict__ s,
    unsigned short* __restrict__ wTall, unsigned short* __restrict__ woT,
    unsigned short* __restrict__ wT, unsigned short* __restrict__ sbf) {
  __shared__ float tile[64][65];
  const int b = blockIdx.x, t = threadIdx.x;
  if (b < 642) {
    const int ntile = b % 107, kt = b / 107;
    const float* src; int Nsrc, nloc0;
    const int ng0 = ntile * 64;
    if (ntile < 32)      { src = wq;   Nsrc = 2048; nloc0 = ng0; }
    else if (ntile < 96) { src = wkv;  Nsrc = 4096; nloc0 = ng0 - 2048; }
    else if (ntile < 99) { src = wqp;  Nsrc = 192;  nloc0 = ng0 - 6144; }
    else                 { src = wkvp; Nsrc = 480;  nloc0 = ng0 - 6336; }
    const int r = t >> 2, cs = (t & 3) * 16;
#pragma unroll
    for (int i = 0; i < 16; i += 4) {
      int n = nloc0 + cs + i;
      float4 v;
      if (n + 3 < Nsrc) v = *(const float4*)(src + (size_t)(kt * 64 + r) * Nsrc + n);
      else {
        v.x = (n + 0 < Nsrc) ? src[(size_t)(kt * 64 + r) * Nsrc + n + 0] : 0.f;
        v.y = (n + 1 < Nsrc) ? src[(size_t)(kt * 64 + r) * Nsrc + n + 1] : 0.f;
        v.z = (n + 2 < Nsrc) ? src[(size_t)(kt * 64 + r) * Nsrc + n + 2] : 0.f;
        v.w = (n + 3 < Nsrc) ? src[(size_t)(kt * 64 + r) * Nsrc + n + 3] : 0.f;
      }
      tile[r][cs + i + 0] = v.x; tile[r][cs + i + 1] = v.y;
      tile[r][cs + i + 2] = v.z; tile[r][cs + i + 3] = v.w;
    }
    __syncthreads();
    const int nr = t >> 2, ks = (t & 3) * 16;
    unsigned short ov[16];
#pragma unroll
    for (int i = 0; i < 16; i++) ov[i] = f2bf(tile[ks + i][nr]);
    unsigned short* dst = wTall + (size_t)(ng0 + nr) * 384 + kt * 64 + ks;
    *(uint4*)(dst) = *(const uint4*)&ov[0];
    *(uint4*)(dst + 8) = *(const uint4*)&ov[8];
  } else if (b < 894) {
    const int idx = b - 642;
    const int kt = idx % 42, ntile = idx / 42;
    const int r = t >> 2, cs = (t & 3) * 16;
#pragma unroll
    for (int i = 0; i < 16; i += 4) {
      float4 v = *(const float4*)(wo + (size_t)(kt * 64 + r) * 384 + ntile * 64 + cs + i);
      tile[r][cs + i + 0] = v.x; tile[r][cs + i + 1] = v.y;
      tile[r][cs + i + 2] = v.z; tile[r][cs + i + 3] = v.w;
    }
    __syncthreads();
    const int nr = t >> 2, ks = (t & 3) * 16;
    unsigned short ov[16];
#pragma unroll
    for (int i = 0; i < 16; i++) ov[i] = f2bf(tile[ks + i][nr]);
    unsigned short* dst = woT + (size_t)(ntile * 64 + nr) * 2688 + kt * 64 + ks;
    *(uint4*)(dst) = *(const uint4*)&ov[0];
    *(uint4*)(dst + 8) = *(const uint4*)&ov[8];
  } else if (b < 918) {
    const int l = (b - 894) * 256 + t;  // 48*128 = 6144
    if (l < 6144) {
      int n = l >> 7, k = l & 127;
      float v = (n < 8) ? wb[k * 8 + n] * 0.5773502691896258f
                        : (n < 40 ? wz[k * 32 + (n - 8)] : 0.f);
      wT[l] = f2bf(v);
    }
  } else {
    const int gid = (b - 918) * 256 + t;       // 24576 threads x 8 elems
    const int off = gid * 8;                   // covers 512*384 = 196608
    float4 a0 = *(const float4*)(s + off);
    float4 a1 = *(const float4*)(s + off + 4);
    *(short8*)(sbf + off) = pack8(a0, a1);
  }
}

// ---------------- mega1: zpass (blocks [0,256)) U proj ([256,1112)) -----------------
// zpass: ping-pong LDS tile of 64 z-rows staged via async global_load_lds (prefetch
// tile T+1 during MFMA compute of tile T); wT B-frags in registers.
__global__ __launch_bounds__(256) void mega1(
    const float* __restrict__ z, const unsigned short* __restrict__ wT,
    const float* __restrict__ bb, const float* __restrict__ bz,
    unsigned short* __restrict__ bbias_tb, unsigned short* __restrict__ pairzT,
    const unsigned short* __restrict__ sbf, const unsigned short* __restrict__ wTall,
    const float* __restrict__ bq, const float* __restrict__ bkv,
    const float* __restrict__ bqp, const float* __restrict__ bkvp,
    unsigned short* __restrict__ qbh, unsigned short* __restrict__ kbh,
    float* __restrict__ vb, float* __restrict__ qpraw, float* __restrict__ kvpraw) {
  const int lane = threadIdx.x & 63, wv = threadIdx.x >> 6;
  const int quad = lane >> 4, m = lane & 15;
  if (blockIdx.x < 256) {
    // ------- zpass: 16 tiles x 64 rows per block, double-buffered LDS -------
    __shared__ __align__(16) float zt[2][64][128];
    __shared__ __align__(16) unsigned short lb[4][8][16];
    __shared__ __align__(16) unsigned short lp[4][32][16];
    short8 bfw[3][4];
#pragma unroll
    for (int nt = 0; nt < 3; nt++)
#pragma unroll
      for (int s = 0; s < 4; s++)
        bfw[nt][s] = *(const short8*)(wT + (size_t)(nt * 16 + m) * 128 + s * 32 + quad * 8);
    float bias[3];
#pragma unroll
    for (int nt = 0; nt < 3; nt++) {
      int c = nt * 16 + m;
      bias[nt] = (c < 8) ? 0.5773502691896258f * bb[c] : (c < 40 ? bz[c - 8] : 0.f);
    }
    const int lrow = lane >> 5, lcol = (lane & 31) * 4;   // staging lane mapping
    // prologue: stage tile 0
    {
      const int Tg0 = blockIdx.x * 16;
#pragma unroll
      for (int i2 = 0; i2 < 8; i2++) {
        const int k = wv * 8 + i2;
        gl_lds16(z + (size_t)(Tg0 * 64 + 2 * k + lrow) * 128 + lcol, &zt[0][2 * k][0]);
      }
    }
    __syncthreads();                      // drains vmcnt -> tile 0 resident
    for (int T = 0; T < 16; T++) {
      const int buf = T & 1;
      const int Tg = blockIdx.x * 16 + T;
      if (T < 15) {                       // async prefetch tile T+1 into buf^1
#pragma unroll
        for (int i2 = 0; i2 < 8; i2++) {
          const int k = wv * 8 + i2;
          gl_lds16(z + (size_t)((Tg + 1) * 64 + 2 * k + lrow) * 128 + lcol,
                   &zt[buf ^ 1][2 * k][0]);
        }
      }
      // compute tile T from LDS
      f32x4 acc[3];
#pragma unroll
      for (int nt = 0; nt < 3; nt++) acc[nt] = (f32x4){0.f, 0.f, 0.f, 0.f};
#pragma unroll
      for (int s = 0; s < 4; s++) {
        const float* zr = &zt[buf][wv * 16 + m][s * 32 + quad * 8];
        float4 a0 = *(const float4*)(zr);
        float4 a1 = *(const float4*)(zr + 4);
        short8 af = pack8(a0, a1);
#pragma unroll
        for (int nt = 0; nt < 3; nt++)
          acc[nt] = __builtin_amdgcn_mfma_f32_16x16x32_bf16(af, bfw[nt][s], acc[nt], 0, 0, 0);
      }
#pragma unroll
      for (int nt = 0; nt < 3; nt++) {
        const int c = nt * 16 + m;
#pragma unroll
        for (int r = 0; r < 4; r++) {
          const float v = acc[nt][r] + bias[nt];
          const int jl = quad * 4 + r;
          if (c < 8)       lb[wv][c][jl] = f2bf(v);
          else if (c < 40) lp[wv][c - 8][jl] = f2bf(v);
        }
      }
      const int row0 = Tg * 64 + wv * 16;
      const int i = row0 >> 9, j0 = row0 & 511;
      if (lane < 16) {
        int c = lane >> 1, half = lane & 1;
        uint4 val = *(const uint4*)&lb[wv][c][half * 8];
        *(uint4*)(bbias_tb + (size_t)c * 262144 + row0 + half * 8) = val;
      }
      {
        int d = lane >> 1, half = lane & 1;
        uint4 val = *(const uint4*)&lp[wv][d][half * 8];
        *(uint4*)(pairzT + ((size_t)i * 32 + d) * 512 + j0 + half * 8) = val;
      }
      __syncthreads();                    // drain prefetch + all waves done with buf
    }
  } else {
    // ------- proj -------
    const int b2 = blockIdx.x - 256;
    const int bx = b2 % 107, row0 = (b2 / 107) * 64;
    const int n0 = bx * 64;
    const unsigned short* srow = sbf + (size_t)(row0 + wv * 16 + m) * 384;
    f32x4 acc[4];
#pragma unroll
    for (int nt = 0; nt < 4; nt++) acc[nt] = (f32x4){0.f, 0.f, 0.f, 0.f};
#pragma unroll
    for (int ksx = 0; ksx < 12; ksx++) {
      const int c0 = ksx * 32 + quad * 8;
      short8 af = *(const short8*)(srow + c0);
#pragma unroll
      for (int nt = 0; nt < 4; nt++) {
        short8 bfw2 = *(const short8*)(wTall + (size_t)(n0 + nt * 16 + m) * 384 + c0);
        acc[nt] = __builtin_amdgcn_mfma_f32_16x16x32_bf16(af, bfw2, acc[nt], 0, 0, 0);
      }
    }
    const int rbase = row0 + wv * 16 + quad * 4;
#pragma unroll
    for (int nt = 0; nt < 4; nt++) {
      const int col = n0 + nt * 16 + m;
      if (n0 < 2048) {
        const float bias = bq[col];
#pragma unroll
        for (int r = 0; r < 4; r++)
          qbh[(size_t)(rbase + r) * 2048 + col] = f2bf(acc[nt][r] + bias);
      } else if (n0 < 6144) {
        const int ckv = col - 2048;
        const float bias = bkv[ckv];
        const int hh = ckv >> 9, c = ckv & 511;
        if (c < 256) {
#pragma unroll
          for (int r = 0; r < 4; r++)
            kbh[(size_t)(rbase + r) * 2048 + hh * 256 + c] = f2bf(acc[nt][r] + bias);
        } else {
#pragma unroll
          for (int r = 0; r < 4; r++)
            vb[(size_t)(rbase + r) * 2048 + hh * 256 + (c - 256)] = acc[nt][r] + bias;
        }
      } else if (n0 < 6336) {
        const int cq = col - 6144;
        const float bias = bqp[cq];
#pragma unroll
        for (int r = 0; r < 4; r++)
          qpraw[(size_t)(rbase + r) * 192 + cq] = acc[nt][r] + bias;
      } else {
        const int ck = col - 6336;
        if (ck < 480) {
          const float bias = bkvp[ck];
#pragma unroll
          for (int r = 0; r < 4; r++)
            kvpraw[(size_t)(rbase + r) * 480 + ck] = acc[nt][r] + bias;
        }
      }
    }
  }
}

// ---------------- mega2: vpt_prep (blocks [0,320)) U pts_planes ([320,336)) ---------
__global__ __launch_bounds__(256) void mega2(
    const float* __restrict__ vb, const float* __restrict__ qpraw,
    const float* __restrict__ kvpraw, const float* __restrict__ rot,
    const float* __restrict__ trans, unsigned short* __restrict__ vptT,
    unsigned short* __restrict__ qptH, unsigned short* __restrict__ qptL,
    unsigned short* __restrict__ kptH, unsigned short* __restrict__ kptL,
    float* __restrict__ qp2g, float* __restrict__ kp2g) {
  __shared__ float tile[64][65];
  const int b = blockIdx.x, t = threadIdx.x;
  if (b < 320) {
    const int jt = b & 7, h = (b >> 3) & 7, part = b >> 6;
    const int j0 = jt * 64;
    if (part < 4) {
      const int c0 = part * 64;
      const int r = t >> 2, cs = (t & 3) * 16;
#pragma unroll
      for (int ii = 0; ii < 16; ii += 4) {
        float4 v = *(const float4*)(vb + (size_t)(j0 + r) * 2048 + h * 256 + c0 + cs + ii);
        tile[r][cs + ii + 0] = v.x; tile[r][cs + ii + 1] = v.y;
        tile[r][cs + ii + 2] = v.z; tile[r][cs + ii + 3] = v.w;
      }
      __syncthreads();
      const int cl = t >> 2, js = (t & 3) * 16;
      unsigned short ov[16];
#pragma unroll
      for (int x = 0; x < 16; x++) ov[x] = f2bf(tile[js + x][cl]);
      unsigned short* dst = vptT + ((size_t)h * 352 + c0 + cl) * 512 + j0 + js;
      *(uint4*)dst = *(const uint4*)&ov[0];
      *(uint4*)(dst + 8) = *(const uint4*)&ov[8];
    } else {
      float (*lds)[37] = (float(*)[37])&tile[0][0];   // 64 x 37 view
      for (int l = t; l < 64 * 36; l += 256) {
        int jl = l / 36, w = l % 36;
        int p = w / 3, d = w % 3;
        const int n = j0 + jl;
        const int pidx = h * 20 + 8 + p;
        const float* kr = kvpraw + (size_t)n * 480;
        float px = kr[pidx], py = kr[160 + pidx], pz = kr[320 + pidx];
        const float* R = rot + n * 9;
        lds[jl][w] = R[d * 3 + 0] * px + R[d * 3 + 1] * py + R[d * 3 + 2] * pz + trans[n * 3 + d];
      }
      __syncthreads();
#pragma unroll
      for (int step = 0; step < 3; step++) {
        int chunk = t + 256 * step;          // < 768 = 96 rows x 8 chunks
        int row = chunk >> 3, js = (chunk & 7) * 8;
        unsigned short ov[8];
#pragma unroll
        for (int x = 0; x < 8; x++) {
          int w = (row < 48) ? row : row - 48;
          float f = (w < 36) ? lds[js + x][w] : 0.f;
          unsigned short hi = f2bf(f);
          ov[x] = (row < 48) ? hi : f2bf(f - bf2f(hi));
        }
        *(uint4*)(vptT + ((size_t)h * 352 + 256 + row) * 512 + j0 + js) = *(const uint4*)&ov[0];
      }
    }
  } else {
    // ------- pts_planes with inline rigid -------
    const int idx = b - 320;
    const int row = (idx & 1) * 256 + t;
    const int h = idx >> 1;
    const float* R  = rot + row * 9;
    const float* tr = trans + row * 3;
    {
      const float* qr = qpraw + (size_t)row * 192;
      unsigned short hi[32], lo[32]; float s2 = 0.f;
#pragma unroll
      for (int p = 0; p < 8; p++) {
        const int pidx = h * 8 + p;
        float px = qr[pidx], py = qr[64 + pidx], pz = qr[128 + pidx];
        float X = R[0] * px + R[1] * py + R[2] * pz + tr[0];
        float Y = R[3] * px + R[4] * py + R[5] * pz + tr[1];
        float Z = R[6] * px + R[7] * py + R[8] * pz + tr[2];
        hi[p * 3 + 0] = f2bf(X); lo[p * 3 + 0] = f2bf(X - bf2f(hi[p * 3 + 0]));
        hi[p * 3 + 1] = f2bf(Y); lo[p * 3 + 1] = f2bf(Y - bf2f(hi[p * 3 + 1]));
        hi[p * 3 + 2] = f2bf(Z); lo[p * 3 + 2] = f2bf(Z - bf2f(hi[p * 3 + 2]));
        s2 += X * X + Y * Y + Z * Z;
      }
#pragma unroll
      for (int w = 24; w < 32; w++) { hi[w] = 0; lo[w] = 0; }
      unsigned short* dh = qptH + ((size_t)h * 512 + row) * 32;
      unsigned short* dl = qptL + ((size_t)h * 512 + row) * 32;
#pragma unroll
      for (int g = 0; g < 4; g++) {
        *(uint4*)(dh + g * 8) = *(const uint4*)&hi[g * 8];
        *(uint4*)(dl + g * 8) = *(const uint4*)&lo[g * 8];
      }
      qp2g[h * 512 + row] = s2;
    }
    {
      const float* kr = kvpraw + (size_t)row * 480;
      unsigned short hi[32], lo[32]; float s2 = 0.f;
#pragma unroll
      for (int p = 0; p < 8; p++) {
        const int pidx = h * 20 + p;
        float px = kr[pidx], py = kr[160 + pidx], pz = kr[320 + pidx];
        float X = R[0] * px + R[1] * py + R[2] * pz + tr[0];
        float Y = R[3] * px + R[4] * py + R[5] * pz + tr[1];
        float Z = R[6] * px + R[7] * py + R[8] * pz + tr[2];
        hi[p * 3 + 0] = f2bf(X); lo[p * 3 + 0] = f2bf(X - bf2f(hi[p * 3 + 0]));
        hi[p * 3 + 1] = f2bf(Y); lo[p * 3 + 1] = f2bf(Y - bf2f(hi[p * 3 + 1]));
        hi[p * 3 + 2] = f2bf(Z); lo[p * 3 + 2] = f2bf(Z - bf2f(hi[p * 3 + 2]));
        s2 += X * X + Y * Y + Z * Z;
      }
#pragma unroll
      for (int w = 24; w < 32; w++) { hi[w] = 0; lo[w] = 0; }
      unsigned short* dh = kptH + ((size_t)h * 512 + row) * 32;
      unsigned short* dl = kptL + ((size_t)h * 512 + row) * 32;
#pragma unroll
      for (int g = 0; g < 4; g++) {
        *(uint4*)(dh + g * 8) = *(const uint4*)&hi[g * 8];
        *(uint4*)(dl + g * 8) = *(const uint4*)&lo[g * 8];
      }
      kp2g[h * 512 + row] = s2;
    }
  }
}

// ---------------- fused logits + softmax + a@[v,pts], 8 waves ------------------------
// grid 256 (1-D): h = bx&7 (XCD-affinity: same-h blocks share per-XCD L2 working set
// kbh/vptT/bbias ~1.2MB), it = bx>>3.
__global__ __launch_bounds__(512) void logits_fused(
    const unsigned short* __restrict__ qbh, const unsigned short* __restrict__ kbh,
    const unsigned short* __restrict__ qptH, const unsigned short* __restrict__ qptL,
    const unsigned short* __restrict__ kptH, const unsigned short* __restrict__ kptL,
    const float* __restrict__ qp2g, const float* __restrict__ kp2g,
    const unsigned short* __restrict__ bbias_tb, const float* __restrict__ mask,
    const float* __restrict__ hwp, const unsigned short* __restrict__ vptT,
    const float* __restrict__ rot, const float* __restrict__ trans,
    unsigned short* __restrict__ attnh, unsigned short* __restrict__ featsb) {
  const int bx = blockIdx.x;
  const int h = bx & 7, it = bx >> 3;
  const int i0 = it * 16;
  __shared__ __align__(16) unsigned short sth[8][16][72], stl[8][16][72];
  __shared__ float redm[16][8], reds[16][8];
  __shared__ float lds_h[16][48], lds_l[16][48];
  const int t = threadIdx.x;
  const int lane = t & 63, wv = t >> 6;
  const int quad = lane >> 4, m = lane & 15;
  const int jw0 = wv * 64;

  // ---- QK^T (4 n-tiles of 16 j each) ----
  f32x4 acc[4];
#pragma unroll
  for (int nt = 0; nt < 4; nt++) acc[nt] = (f32x4){0.f, 0.f, 0.f, 0.f};
  const unsigned short* qrow = qbh + (size_t)(i0 + m) * 2048 + h * 256;
#pragma unroll
  for (int s = 0; s < 8; s++) {
    short8 af = *(const short8*)(qrow + s * 32 + quad * 8);
#pragma unroll
    for (int nt = 0; nt < 4; nt++) {
      short8 bfr = *(const short8*)(kbh + (size_t)(jw0 + nt * 16 + m) * 2048 + h * 256 + s * 32 + quad * 8);
      acc[nt] = __builtin_amdgcn_mfma_f32_16x16x32_bf16(af, bfr, acc[nt], 0, 0, 0);
    }
  }

  // ---- point cross-term (hi/lo split) from global planes ----
  short8 aqh = *(const short8*)(qptH + ((size_t)h * 512 + i0 + m) * 32 + quad * 8);
  short8 aql = *(const short8*)(qptL + ((size_t)h * 512 + i0 + m) * 32 + quad * 8);
  f32x4 accp[4];
#pragma unroll
  for (int nt = 0; nt < 4; nt++) {
    const size_t krow = ((size_t)h * 512 + jw0 + nt * 16 + m) * 32 + quad * 8;
    short8 bkh = *(const short8*)(kptH + krow);
    short8 bkl = *(const short8*)(kptL + krow);
    f32x4 p = (f32x4){0.f, 0.f, 0.f, 0.f};
    p = __builtin_amdgcn_mfma_f32_16x16x32_bf16(aqh, bkh, p, 0, 0, 0);
    p = __builtin_amdgcn_mfma_f32_16x16x32_bf16(aqh, bkl, p, 0, 0, 0);
    p = __builtin_amdgcn_mfma_f32_16x16x32_bf16(aql, bkh, p, 0, 0, 0);
    accp[nt] = p;
  }

  // ---- logits ----
  const float c1 = 0.03608439182435161f;                         // 1/sqrt(768)
  const float hw = log1pf(expf(hwp[h])) * 0.09622504486493764f;  // softplus*sqrt(1/108)
  float qp2v[4];
#pragma unroll
  for (int r = 0; r < 4; r++) qp2v[r] = qp2g[h * 512 + i0 + quad * 4 + r];
  float lg[4][4];
  float rmax[4] = {-1e30f, -1e30f, -1e30f, -1e30f};
#pragma unroll
  for (int nt = 0; nt < 4; nt++) {
    const int j = jw0 + nt * 16 + m;
    const float kp2v = kp2g[h * 512 + j];
    const float mj = mask[j];
#pragma unroll
    for (int r = 0; r < 4; r++) {
      const int il = quad * 4 + r;
      const float pt = qp2v[r] + kp2v - 2.f * accp[nt][r];
      float v = c1 * acc[nt][r]
              + bf2f(bbias_tb[(size_t)h * 262144 + (size_t)(i0 + il) * 512 + j])
              - 0.5f * hw * pt
              + 100000.f * (mask[i0 + il] * mj - 1.f);
      lg[nt][r] = v;
      rmax[r] = fmaxf(rmax[r], v);
    }
  }
  // ---- softmax (cross-lane within 16-lane group, then cross-wave via LDS) ----
#pragma unroll
  for (int r = 0; r < 4; r++) {
#pragma unroll
    for (int off = 1; off < 16; off <<= 1) rmax[r] = fmaxf(rmax[r], __shfl_xor(rmax[r], off));
  }
  if (m == 0) {
#pragma unroll
    for (int r = 0; r < 4; r++) redm[quad * 4 + r][wv] = rmax[r];
  }
  __syncthreads();
  float rowm[4], rsum[4];
#pragma unroll
  for (int r = 0; r < 4; r++) {
    const int il = quad * 4 + r;
    float m0 = fmaxf(fmaxf(redm[il][0], redm[il][1]), fmaxf(redm[il][2], redm[il][3]));
    float m1 = fmaxf(fmaxf(redm[il][4], redm[il][5]), fmaxf(redm[il][6], redm[il][7]));
    rowm[r] = fmaxf(m0, m1);
    rsum[r] = 0.f;
  }
#pragma unroll
  for (int nt = 0; nt < 4; nt++)
#pragma unroll
    for (int r = 0; r < 4; r++) {
      float e = __expf(lg[nt][r] - rowm[r]);
      lg[nt][r] = e;
      rsum[r] += e;
    }
#pragma unroll
  for (int r = 0; r < 4; r++) {
#pragma unroll
    for (int off = 1; off < 16; off <<= 1) rsum[r] += __shfl_xor(rsum[r], off);
  }
  if (m == 0) {
#pragma unroll
    for (int r = 0; r < 4; r++) reds[quad * 4 + r][wv] = rsum[r];
  }
  __syncthreads();
  float inv[4];
#pragma unroll
  for (int r = 0; r < 4; r++) {
    const int il = quad * 4 + r;
    float s0 = (reds[il][0] + reds[il][1]) + (reds[il][2] + reds[il][3]);
    float s1 = (reds[il][4] + reds[il][5]) + (reds[il][6] + reds[il][7]);
    inv[r] = 1.f / (s0 + s1);
  }
  // ---- a -> bf16 hi/lo into LDS ----
#pragma unroll
  for (int nt = 0; nt < 4; nt++)
#pragma unroll
    for (int r = 0; r < 4; r++) {
      const int il = quad * 4 + r;
      float a = lg[nt][r] * inv[r];
      unsigned short hi = f2bf(a);
      sth[wv][il][nt * 16 + m] = hi;
      stl[wv][il][nt * 16 + m] = f2bf(a - bf2f(hi));
    }
  __syncthreads();
  // attnh global (hi only, for o_pair), coalesced: 16 rows x 8 segs of 8 per wave
#pragma unroll
  for (int step = 0; step < 2; step++) {
    const int idx = lane + 64 * step;        // 0..127
    const int il = idx >> 3, seg = idx & 7;
    uint4 vh = *(const uint4*)&sth[wv][il][seg * 8];
    *(uint4*)(attnh + ((size_t)h * 512 + i0 + il) * 512 + jw0 + seg * 8) = vh;
  }

  // ---- phase 2: a @ vptT (A-frags from LDS across all 8 j-slices) ----
  const int nt0 = (wv < 6) ? wv * 3 : 18 + (wv - 6) * 2;
  const int ncnt = (wv < 6) ? 3 : 2;
  f32x4 vacc[3];
#pragma unroll
  for (int k = 0; k < 3; k++) vacc[k] = (f32x4){0.f, 0.f, 0.f, 0.f};
  const unsigned short* vbase = vptT + (size_t)h * 352 * 512;
#pragma unroll
  for (int s = 0; s < 16; s++) {
    const int wsrc = s >> 1, col = (s & 1) * 32 + quad * 8;
    short8 ah = *(const short8*)&sth[wsrc][m][col];
    short8 al = *(const short8*)&stl[wsrc][m][col];
    const int ko = s * 32 + quad * 8;
#pragma unroll
    for (int k = 0; k < 3; k++) {
      if (k < ncnt) {
        const int nt = nt0 + k;
        short8 bfr = *(const short8*)(vbase + (size_t)(nt * 16 + m) * 512 + ko);
        vacc[k] = __builtin_amdgcn_mfma_f32_16x16x32_bf16(ah, bfr, vacc[k], 0, 0, 0);
        if (nt >= 16 && nt < 19)
          vacc[k] = __builtin_amdgcn_mfma_f32_16x16x32_bf16(al, bfr, vacc[k], 0, 0, 0);
      }
    }
  }
#pragma unroll
  for (int k = 0; k < 3; k++) {
    if (k < ncnt) {
      const int nt = nt0 + k;
      if (nt < 16) {
#pragma unroll
        for (int r = 0; r < 4; r++)
          featsb[(size_t)(i0 + quad * 4 + r) * 2688 + h * 256 + nt * 16 + m] = f2bf(vacc[k][r]);
      } else if (nt < 19) {
        const int w = (nt - 16) * 16 + m;
#pragma unroll
        for (int r = 0; r < 4; r++) if (w < 36) lds_h[quad * 4 + r][w] = vacc[k][r];
      } else {
        const int w = (nt - 19) * 16 + m;
#pragma unroll
        for (int r = 0; r < 4; r++) if (w < 36) lds_l[quad * 4 + r][w] = vacc[k][r];
      }
    }
  }
  __syncthreads();
  if (t < 192) {
    const int il = t / 12, p = t % 12, irow = i0 + il;
    const float* R = rot + irow * 9;
    const float* tr = trans + irow * 3;
    float x  = lds_h[il][p * 3 + 0] + lds_l[il][p * 3 + 0] - tr[0];
    float y  = lds_h[il][p * 3 + 1] + lds_l[il][p * 3 + 1] - tr[1];
    float zz = lds_h[il][p * 3 + 2] + lds_l[il][p * 3 + 2] - tr[2];
    float o0 = R[0] * x + R[3] * y + R[6] * zz;   // R^T v
    float o1 = R[1] * x + R[4] * y + R[7] * zz;
    float o2 = R[2] * x + R[5] * y + R[8] * zz;
    float nrm = sqrtf(o0 * o0 + o1 * o1 + o2 * o2 + 1e-8f);
    unsigned short* fr = featsb + (size_t)irow * 2688 + 2048;
    fr[h * 12 + p]       = f2bf(o0);
    fr[96 + h * 12 + p]  = f2bf(o1);
    fr[192 + h * 12 + p] = f2bf(o2);
    fr[288 + h * 12 + p] = f2bf(nrm);
  }
}

// ---------------- o_pair: one i per block, 4 waves K-split + LDS reduce --------------
// grid 512: 4x the wave-parallelism of the old 128-block version, 1/4 serial chain.
__global__ __launch_bounds__(256) void o_pair_mfma(
    const unsigned short* __restrict__ attnh, const unsigned short* __restrict__ pairzT,
    unsigned short* __restrict__ featsb) {
  const int lane = threadIdx.x & 63, wv = threadIdx.x >> 6;
  const int quad = lane >> 4, m = lane & 15;
  const int i = blockIdx.x;                  // 512 blocks
  __shared__ float red[4][2][64][4];
  f32x4 acc[2];
  acc[0] = (f32x4){0.f, 0.f, 0.f, 0.f};
  acc[1] = (f32x4){0.f, 0.f, 0.f, 0.f};
#pragma unroll
  for (int s4 = 0; s4 < 4; s4++) {
    const int s = wv * 4 + s4;
    const int ko = s * 32 + quad * 8;
    short8 af = *(const short8*)(attnh + (size_t)(m & 7) * 262144 + (size_t)i * 512 + ko);
#pragma unroll
    for (int nt = 0; nt < 2; nt++) {
      short8 bfr = *(const short8*)(pairzT + ((size_t)i * 32 + nt * 16 + m) * 512 + ko);
      acc[nt] = __builtin_amdgcn_mfma_f32_16x16x32_bf16(af, bfr, acc[nt], 0, 0, 0);
    }
  }
#pragma unroll
  for (int nt = 0; nt < 2; nt++)
#pragma unroll
    for (int r = 0; r < 4; r++) red[wv][nt][lane][r] = acc[nt][r];
  __syncthreads();
  if (wv == 0 && quad < 2) {
#pragma unroll
    for (int nt = 0; nt < 2; nt++)
#pragma unroll
      for (int r = 0; r < 4; r++) {
        float sum = (red[0][nt][lane][r] + red[1][nt][lane][r])
                  + (red[2][nt][lane][r] + red[3][nt][lane][r]);
        const int hh = quad * 4 + r, d = nt * 16 + m;
        featsb[(size_t)i * 2688 + 2432 + hh * 32 + d] = f2bf(sum);
      }
  }
}

// ---------------- out = featsb @ woT^T + bo: 8 waves, K-split pairs + LDS reduce ----
__global__ __launch_bounds__(512) void out_mfma(
    const unsigned short* __restrict__ featsb, const unsigned short* __restrict__ woT,
    const float* __restrict__ bo, float* __restrict__ out) {
  const int it = blockIdx.x, ng = blockIdx.y;   // grid (32, 6)
  const int t = threadIdx.x;
  const int lane = t & 63, w8 = t >> 6;
  const int wn = w8 & 3, wk = w8 >> 2;          // wn: n-tile, wk: K-half
  const int quad = lane >> 4, m = lane & 15;
  const int i0 = it * 16, n0 = (ng * 4 + wn) * 16;
  const unsigned short* arow = featsb + (size_t)(i0 + m) * 2688 + wk * 1344;
  const unsigned short* brow = woT + (size_t)(n0 + m) * 2688 + wk * 1344;
  f32x4 acc = (f32x4){0.f, 0.f, 0.f, 0.f};
#pragma unroll 6
  for (int s = 0; s < 42; s++) {
    const int ko = s * 32 + quad * 8;
    short8 af = *(const short8*)(arow + ko);
    short8 bf = *(const short8*)(brow + ko);
    acc = __builtin_amdgcn_mfma_f32_16x16x32_bf16(af, bf, acc, 0, 0, 0);
  }
  __shared__ float red[4][64][4];
  if (wk == 1) {
#pragma unroll
    for (int r = 0; r < 4; r++) red[wn][lane][r] = acc[r];
  }
  __syncthreads();
  if (wk == 0) {
    const float bias = bo[n0 + m];
#pragma unroll
    for (int r = 0; r < 4; r++)
      out[(size_t)(i0 + quad * 4 + r) * 384 + n0 + m] = acc[r] + red[wn][lane][r] + bias;
  }
}

extern "C" void kernel_launch(void* const* d_in, const int* in_sizes, int n_in,
                              void* d_out, int out_size, void* d_ws, size_t ws_size,
                              hipStream_t stream) {
  const float* s     = (const float*)d_in[0];
  const float* z     = (const float*)d_in[1];
  const float* rot   = (const float*)d_in[2];
  const float* trans = (const float*)d_in[3];
  const float* mask  = (const float*)d_in[4];
  const float* wq    = (const float*)d_in[5];
  const float* bq    = (const float*)d_in[6];
  const float* wkv   = (const float*)d_in[7];
  const float* bkv   = (const float*)d_in[8];
  const float* wqp   = (const float*)d_in[9];
  const float* bqp   = (const float*)d_in[10];
  const float* wkvp  = (const float*)d_in[11];
  const float* bkvp  = (const float*)d_in[12];
  const float* wb    = (const float*)d_in[13];
  const float* bb    = (const float*)d_in[14];
  const float* wz    = (const float*)d_in[15];
  const float* bz    = (const float*)d_in[16];
  const float* hwp   = (const float*)d_in[17];
  const float* wo    = (const float*)d_in[18];
  const float* bo    = (const float*)d_in[19];
  float* out = (float*)d_out;

  float* ws = (float*)d_ws;
  unsigned short* qbh   = (unsigned short*)(ws + OFF_QBH);
  unsigned short* kbh   = (unsigned short*)(ws + OFF_KBH);
  float* vb      = ws + OFF_VB;
  float* qpraw   = ws + OFF_QPRAW;
  float* kvpraw  = ws + OFF_KVPRAW;
  unsigned short* bbias_tb = (unsigned short*)(ws + OFF_BBIAS);
  unsigned short* pairzT   = (unsigned short*)(ws + OFF_PAIRZT);
  unsigned short* attnh    = (unsigned short*)(ws + OFF_ATTNH);
  unsigned short* featsb   = (unsigned short*)(ws + OFF_FEATSB);
  unsigned short* wT    = (unsigned short*)(ws + OFF_WCAT);
  unsigned short* wTall = (unsigned short*)(ws + OFF_WTALL);
  unsigned short* vptT  = (unsigned short*)(ws + OFF_VPT);
  unsigned short* woT   = (unsigned short*)(ws + OFF_WOT);
  unsigned short* qptH  = (unsigned short*)(ws + OFF_QPTH);
  unsigned short* qptL  = (unsigned short*)(ws + OFF_QPTL);
  unsigned short* kptH  = (unsigned short*)(ws + OFF_KPTH);
  unsigned short* kptL  = (unsigned short*)(ws + OFF_KPTL);
  float* qp2g = ws + OFF_QP2;
  float* kp2g = ws + OFF_KP2;
  unsigned short* sbf = (unsigned short*)(ws + OFF_SBF);

  prep_all<<<1014, 256, 0, stream>>>(wq, wkv, wqp, wkvp, wo, wb, wz, s,
                                     wTall, woT, wT, sbf);
  mega1<<<1112, 256, 0, stream>>>(z, wT, bb, bz, bbias_tb, pairzT,
                                  sbf, wTall, bq, bkv, bqp, bkvp,
                                  qbh, kbh, vb, qpraw, kvpraw);
  mega2<<<336, 256, 0, stream>>>(vb, qpraw, kvpraw, rot, trans, vptT,
                                 qptH, qptL, kptH, kptL, qp2g, kp2g);
  logits_fused<<<256, 512, 0, stream>>>(qbh, kbh, qptH, qptL, kptH, kptL,
                                        qp2g, kp2g, bbias_tb, mask, hwp,
                                        vptT, rot, trans, attnh, featsb);
  o_pair_mfma<<<512, 256, 0, stream>>>(attnh, pairzT, featsb);
  out_mfma<<<dim3(32, 6), 512, 0, stream>>>(featsb, woT, bo, out);
}